// Round 15
// baseline (433.821 us; speedup 1.0000x reference)
//
#include <hip/hip_runtime.h>

constexpr int NN  = 100000;    // nodes
constexpr int NE  = 3200000;   // edges
constexpr int HID = 64;
constexpr int TL  = 4;

constexpr int BIN_SHIFT = 9;                              // 512 nodes / bin
constexpr int BIN_NODES = 1 << BIN_SHIFT;
constexpr int NBINS     = (NN + BIN_NODES - 1) / BIN_NODES;  // 196
constexpr int BINCAP    = 18944;   // mean 16327 edges/bin, ~+20 sigma
constexpr int TILE_E    = 2048;    // edges per scatter tile (8/thread)
constexpr int PAD       = 40;      // padded neighbor-list length (P(deg>40)~7%)

typedef unsigned short ushort_t;
typedef unsigned int uint_t;
typedef __attribute__((ext_vector_type(8))) short bf16x8;   // MFMA A/B frag
typedef __attribute__((ext_vector_type(4))) float f32x4;    // MFMA C/D frag
typedef __attribute__((ext_vector_type(2))) float f32x2;    // v_pk_add_f32 pair

__device__ __forceinline__ ushort_t f2b(float f) {       // fp32 -> bf16 RNE
  uint_t u = __float_as_uint(f);
  u += 0x7fff + ((u >> 16) & 1);
  return (ushort_t)(u >> 16);
}
__device__ __forceinline__ float b2f(ushort_t h) {
  return __uint_as_float(((uint_t)h) << 16);
}

// Merged edge pass with TILE-SORTED write-out. Scan via per-wave shfl_up
// (2 barriers/tile instead of 32). One tile (2048 edges) per block.
__global__ __launch_bounds__(256) void escatter_kernel(
    const int* __restrict__ ei, const float* __restrict__ ea,
    int* __restrict__ bincursor, uint_t* __restrict__ gbin,
    int* __restrict__ bincursor2, uint_t* __restrict__ gbin2) {
  __shared__ int hist1[256], hist2[256];
  __shared__ int base1[NBINS], base2[NBINS];
  __shared__ int offs1[NBINS], offs2[NBINS];
  __shared__ int wt1[4], wt2[4];
  __shared__ uint_t srec[TILE_E];
  __shared__ int    sdst[TILE_E];
  int tid = threadIdx.x;
  int tb = blockIdx.x * TILE_E;
  hist1[tid] = 0; hist2[tid] = 0;
  __syncthreads();
  uint_t rec1[8], rec2[8]; int bn1[8], bn2[8], rk1[8], rk2[8];
  #pragma unroll
  for (int j = 0; j < 8; ++j) {
    int e = tb + tid + j * 256;
    bn1[j] = -1; bn2[j] = -1;
    rk1[j] = 0; rk2[j] = 0; rec1[j] = 0; rec2[j] = 0;
    if (e < NE) {
      int s = ei[e];
      int d = ei[NE + e];
      uint_t q = (uint_t)(int)(ea[e] * 8388608.0f);   // ea in [0,1): 23 bits
      bn1[j] = d >> BIN_SHIFT;
      rec1[j] = ((uint_t)s << BIN_SHIFT) | (uint_t)(d & (BIN_NODES - 1));
      rk1[j] = atomicAdd(&hist1[bn1[j]], 1);
      bn2[j] = s >> BIN_SHIFT;
      rec2[j] = (q << BIN_SHIFT) | (uint_t)(s & (BIN_NODES - 1));
      rk2[j] = atomicAdd(&hist2[bn2[j]], 1);
    }
  }
  __syncthreads();
  int c1 = hist1[tid], c2 = hist2[tid];     // per-bin counts (this tile)
  // inclusive scan: per-wave shfl scan + cross-wave combine
  int lane = tid & 63;
  int wvx = tid >> 6;
  int v1 = c1, v2 = c2;
  #pragma unroll
  for (int o = 1; o < 64; o <<= 1) {
    int t1 = __shfl_up(v1, o);
    int t2 = __shfl_up(v2, o);
    if (lane >= o) { v1 += t1; v2 += t2; }
  }
  if (lane == 63) { wt1[wvx] = v1; wt2[wvx] = v2; }
  __syncthreads();
  for (int k = 0; k < wvx; ++k) { v1 += wt1[k]; v2 += wt2[k]; }
  hist1[tid] = v1; hist2[tid] = v2;
  __syncthreads();
  if (tid < NBINS) {
    offs1[tid] = hist1[tid] - c1;           // exclusive scan
    offs2[tid] = hist2[tid] - c2;
    base1[tid] = c1 ? atomicAdd(&bincursor[tid], c1) : 0;
    base2[tid] = c2 ? atomicAdd(&bincursor2[tid], c2) : 0;
  }
  __syncthreads();
  int total1 = hist1[NBINS - 1];
  int total2 = hist2[NBINS - 1];
  // ---- stream 1: stage sorted, write out ----
  #pragma unroll
  for (int j = 0; j < 8; ++j) {
    if (bn1[j] >= 0) {
      int p = offs1[bn1[j]] + rk1[j];
      int gp = base1[bn1[j]] + rk1[j];
      srec[p] = rec1[j];
      sdst[p] = (gp < BINCAP) ? (bn1[j] * BINCAP + gp) : -1;
    }
  }
  __syncthreads();
  for (int t = tid; t < total1; t += 256) {
    int g = sdst[t];
    if (g >= 0) gbin[g] = srec[t];
  }
  __syncthreads();
  // ---- stream 2: reuse staging buffers ----
  #pragma unroll
  for (int j = 0; j < 8; ++j) {
    if (bn2[j] >= 0) {
      int p = offs2[bn2[j]] + rk2[j];
      int gp = base2[bn2[j]] + rk2[j];
      srec[p] = rec2[j];
      sdst[p] = (gp < BINCAP) ? (bn2[j] * BINCAP + gp) : -1;
    }
  }
  __syncthreads();
  for (int t = tid; t < total2; t += 256) {
    int g = sdst[t];
    if (g >= 0) gbin2[g] = srec[t];
  }
}

// Fallback single-stream scatters (used when workspace can't fit gbin2).
__global__ __launch_bounds__(256) void binscatter_kernel(
    const int* __restrict__ ei, int* __restrict__ bincursor,
    uint_t* __restrict__ gbin) {
  __shared__ int hist[NBINS];
  __shared__ int base[NBINS];
  int tid = threadIdx.x;
  int ntiles = (NE + TILE_E - 1) / TILE_E;
  for (int tile = blockIdx.x; tile < ntiles; tile += gridDim.x) {
    int tb = tile * TILE_E;
    for (int i = tid; i < NBINS; i += 256) hist[i] = 0;
    __syncthreads();
    uint_t rec[8]; int bn[8]; int rk[8];
    #pragma unroll
    for (int j = 0; j < 8; ++j) {
      int e = tb + tid + j * 256;
      bn[j] = -1; rk[j] = 0; rec[j] = 0;
      if (e < NE) {
        int s = ei[e];
        int d = ei[NE + e];
        bn[j] = d >> BIN_SHIFT;
        rec[j] = ((uint_t)s << BIN_SHIFT) | (uint_t)(d & (BIN_NODES - 1));
        rk[j] = atomicAdd(&hist[bn[j]], 1);
      }
    }
    __syncthreads();
    for (int i = tid; i < NBINS; i += 256) {
      int c = hist[i];
      base[i] = c ? atomicAdd(&bincursor[i], c) : 0;
    }
    __syncthreads();
    #pragma unroll
    for (int j = 0; j < 8; ++j) {
      if (bn[j] >= 0) {
        int pos = base[bn[j]] + rk[j];
        if (pos < BINCAP) gbin[(size_t)bn[j] * BINCAP + pos] = rec[j];
      }
    }
    __syncthreads();
  }
}

__global__ __launch_bounds__(256) void sbinscatter_kernel(
    const int* __restrict__ ei, const float* __restrict__ ea,
    int* __restrict__ bincursor2, uint_t* __restrict__ gbin) {
  __shared__ int hist[NBINS];
  __shared__ int base[NBINS];
  int tid = threadIdx.x;
  int ntiles = (NE + TILE_E - 1) / TILE_E;
  for (int tile = blockIdx.x; tile < ntiles; tile += gridDim.x) {
    int tb = tile * TILE_E;
    for (int i = tid; i < NBINS; i += 256) hist[i] = 0;
    __syncthreads();
    uint_t rec[8]; int bn[8]; int rk[8];
    #pragma unroll
    for (int j = 0; j < 8; ++j) {
      int e = tb + tid + j * 256;
      bn[j] = -1; rk[j] = 0; rec[j] = 0;
      if (e < NE) {
        int s = ei[e];
        uint_t q = (uint_t)(int)(ea[e] * 8388608.0f);
        bn[j] = s >> BIN_SHIFT;
        rec[j] = (q << BIN_SHIFT) | (uint_t)(s & (BIN_NODES - 1));
        rk[j] = atomicAdd(&hist[bn[j]], 1);
      }
    }
    __syncthreads();
    for (int i = tid; i < NBINS; i += 256) {
      int c = hist[i];
      base[i] = c ? atomicAdd(&bincursor2[i], c) : 0;
    }
    __syncthreads();
    #pragma unroll
    for (int j = 0; j < 8; ++j) {
      if (bn[j] >= 0) {
        int pos = base[bn[j]] + rk[j];
        if (pos < BINCAP) gbin[(size_t)bn[j] * BINCAP + pos] = rec[j];
      }
    }
    __syncthreads();
  }
}

// K4: one block per bin; LDS cursors; scatter src into colidx.
// Pads slots [cur, PAD) with sentinel NN (zero row in ybuf): aggr main path
// reads exactly PAD slots unconditionally.
__global__ __launch_bounds__(256) void bucket_kernel(
    const uint_t* __restrict__ gbin, const int* __restrict__ bincursor,
    int* __restrict__ colidx, int* __restrict__ cnt, int cap) {
  __shared__ int cur[BIN_NODES];
  int b = blockIdx.x;
  int tid = threadIdx.x;
  for (int i = tid; i < BIN_NODES; i += 256) cur[i] = 0;
  __syncthreads();
  int cb = min(bincursor[b], BINCAP);
  const uint_t* g = gbin + (size_t)b * BINCAP;
  for (int i = tid; i < cb; i += 256) {
    uint_t r = g[i];
    int dl = (int)(r & (BIN_NODES - 1));
    int src = (int)(r >> BIN_SHIFT);
    int pos = atomicAdd(&cur[dl], 1);
    int n = (b << BIN_SHIFT) + dl;
    if (pos < cap) colidx[(size_t)n * cap + pos] = src;
  }
  __syncthreads();
  for (int i = tid; i < BIN_NODES; i += 256) {
    int n = (b << BIN_SHIFT) + i;
    if (n < NN) cnt[n] = min(cur[i], cap);
  }
  for (int gsl = tid; gsl < BIN_NODES * 64; gsl += 256) {
    int i = gsl >> 6;
    int s = gsl & 63;
    int n = (b << BIN_SHIFT) + i;
    if (n < NN && s < PAD && s >= cur[i]) colidx[(size_t)n * cap + s] = NN;
  }
}

// K5b: one block per bin; 512-int LDS accumulator; coalesced s3i store.
__global__ __launch_bounds__(256) void s3bucket_kernel(
    const uint_t* __restrict__ gbin, const int* __restrict__ bincursor2,
    int* __restrict__ s3i) {
  __shared__ int acc[BIN_NODES];
  int b = blockIdx.x;
  int tid = threadIdx.x;
  for (int i = tid; i < BIN_NODES; i += 256) acc[i] = 0;
  __syncthreads();
  int cb = min(bincursor2[b], BINCAP);
  const uint_t* g = gbin + (size_t)b * BINCAP;
  for (int i = tid; i < cb; i += 256) {
    uint_t r = g[i];
    atomicAdd(&acc[r & (BIN_NODES - 1)], (int)(r >> BIN_SHIFT));
  }
  __syncthreads();
  for (int i = tid; i < BIN_NODES; i += 256) {
    int n = (b << BIN_SHIFT) + i;
    if (n < NN) s3i[n] = acc[i];
  }
}

// fp32 x -> bf16 (RNE), vectorized 4-wide.
__global__ void conv_kernel(const float* __restrict__ x, ushort_t* __restrict__ xb) {
  int i = blockIdx.x * blockDim.x + threadIdx.x;
  if (i * 4 >= NN * HID) return;
  const float4 v = *reinterpret_cast<const float4*>(&x[i * 4]);
  ushort4 o;
  o.x = f2b(v.x); o.y = f2b(v.y); o.z = f2b(v.z); o.w = f2b(v.w);
  *reinterpret_cast<ushort4*>(&xb[i * 4]) = o;
}

// W2 [l][k][h] fp32 -> W2T [l][h][k] bf16; W7 [k][h] -> W7T [h][k] bf16.
__global__ void wconv_kernel(const float* __restrict__ W2,
                             const float* __restrict__ W7,
                             ushort_t* __restrict__ w2t,
                             ushort_t* __restrict__ w7t) {
  int i = blockIdx.x * blockDim.x + threadIdx.x;
  int tot2 = TL * HID * HID;
  if (i < tot2) {
    int l = i >> 12, r = i & 4095, h = r >> 6, k = r & 63;
    w2t[i] = f2b(W2[(size_t)l * 4096 + k * 64 + h]);
  } else if (i < tot2 + HID * HID) {
    int j = i - tot2, h = j >> 6, k = j & 63;
    w7t[j] = f2b(W7[k * 64 + h]);
  }
}

// y = x @ W2 via MFMA. One wave = 32 nodes (two 16-row tiles sharing B).
__global__ __launch_bounds__(256) void dense_kernel(
    const ushort_t* __restrict__ xin, const ushort_t* __restrict__ wt,
    ushort_t* __restrict__ yout) {
  int lane = threadIdx.x & 63;
  int wv = (blockIdx.x * blockDim.x + threadIdx.x) >> 6;
  int n0 = wv * 32;
  if (n0 >= NN) return;
  int row = lane & 15;
  int ks = (lane >> 4) * 8;
  bf16x8 a0 = *(const bf16x8*)&xin[(size_t)(n0 + row) * HID + ks];
  bf16x8 a1 = *(const bf16x8*)&xin[(size_t)(n0 + row) * HID + 32 + ks];
  bf16x8 a2 = *(const bf16x8*)&xin[(size_t)(n0 + 16 + row) * HID + ks];
  bf16x8 a3 = *(const bf16x8*)&xin[(size_t)(n0 + 16 + row) * HID + 32 + ks];
  #pragma unroll
  for (int ct = 0; ct < 4; ++ct) {
    bf16x8 b0 = *(const bf16x8*)&wt[(ct * 16 + row) * HID + ks];
    bf16x8 b1 = *(const bf16x8*)&wt[(ct * 16 + row) * HID + 32 + ks];
    f32x4 acc0 = {0.f, 0.f, 0.f, 0.f};
    f32x4 acc1 = {0.f, 0.f, 0.f, 0.f};
    acc0 = __builtin_amdgcn_mfma_f32_16x16x32_bf16(a0, b0, acc0, 0, 0, 0);
    acc0 = __builtin_amdgcn_mfma_f32_16x16x32_bf16(a1, b1, acc0, 0, 0, 0);
    acc1 = __builtin_amdgcn_mfma_f32_16x16x32_bf16(a2, b0, acc1, 0, 0, 0);
    acc1 = __builtin_amdgcn_mfma_f32_16x16x32_bf16(a3, b1, acc1, 0, 0, 0);
    int rr = (lane >> 4) * 4;
    #pragma unroll
    for (int r = 0; r < 4; ++r) {
      yout[(size_t)(n0 + rr + r) * HID + ct * 16 + row] = f2b(acc0[r]);
      yout[(size_t)(n0 + 16 + rr + r) * HID + ct * 16 + row] = f2b(acc1[r]);
    }
  }
}

// Gather-sum + elementwise epilogue. TWO nodes per wave: 32 lanes per node,
// 4 row-groups x 8 lanes (uint4 = 8 bf16). Static PAD(=40)-row padded main
// path (10 gather insts/node); predicated tail for deg in (PAD, cap].
// Accumulators are float2 pairs to map onto v_pk_add_f32.
__global__ __launch_bounds__(256) void aggr_kernel(
    const ushort_t* __restrict__ yin, ushort_t* __restrict__ xout,
    const int* __restrict__ cnt, const int* __restrict__ colidx, int cap,
    const float* __restrict__ x_tag, const int* __restrict__ s3i,
    const float* __restrict__ W1l, const float* __restrict__ W4l) {
  int lane = threadIdx.x & 63;
  int wv = (blockIdx.x * blockDim.x + threadIdx.x) >> 6;
  int n0 = wv * 2;
  if (n0 >= NN) return;
  int half = lane >> 5;                  // node select (n0 or n0+1)
  int n = n0 + half;
  int grp = (lane >> 3) & 3;             // 4 row-groups of 8 lanes
  int sub = lane & 7;
  const int* cl = colidx + (size_t)n * cap + grp;   // slot j*4+grp
  f32x2 g0 = {0.f, 0.f}, g1 = {0.f, 0.f}, g2 = {0.f, 0.f}, g3 = {0.f, 0.f};
  uint4 w[10];
  #pragma unroll
  for (int j = 0; j < 10; ++j) {
    int c = cl[j * 4];                   // same base reg, imm offsets
    w[j] = *reinterpret_cast<const uint4*>(&yin[(size_t)c * HID + sub * 8]);
  }
  #pragma unroll
  for (int j = 0; j < 10; ++j) {
    g0 += (f32x2){__uint_as_float(w[j].x << 16), __uint_as_float(w[j].x & 0xffff0000u)};
    g1 += (f32x2){__uint_as_float(w[j].y << 16), __uint_as_float(w[j].y & 0xffff0000u)};
    g2 += (f32x2){__uint_as_float(w[j].z << 16), __uint_as_float(w[j].z & 0xffff0000u)};
    g3 += (f32x2){__uint_as_float(w[j].w << 16), __uint_as_float(w[j].w & 0xffff0000u)};
  }
  int deg = cnt[n];
  if (__any(deg > PAD)) {                // tail for deg in (PAD, cap<=96]
    int t2 = deg - PAD;
    const int* ct2 = colidx + (size_t)n * cap + PAD;
    for (int jt = 0; jt < 14; ++jt) {
      int idx = jt * 4 + grp;
      if (idx < t2) {
        int c = ct2[idx];
        uint4 ww = *reinterpret_cast<const uint4*>(&yin[(size_t)c * HID + sub * 8]);
        g0 += (f32x2){__uint_as_float(ww.x << 16), __uint_as_float(ww.x & 0xffff0000u)};
        g1 += (f32x2){__uint_as_float(ww.y << 16), __uint_as_float(ww.y & 0xffff0000u)};
        g2 += (f32x2){__uint_as_float(ww.z << 16), __uint_as_float(ww.z & 0xffff0000u)};
        g3 += (f32x2){__uint_as_float(ww.w << 16), __uint_as_float(ww.w & 0xffff0000u)};
      }
    }
  }
  float f0 = g0[0], f1 = g0[1], f2 = g1[0], f3 = g1[1];
  float f4 = g2[0], f5 = g2[1], f6 = g3[0], f7 = g3[1];
  // reduce across 4 row-groups (stays within each 32-lane half)
  #pragma unroll
  for (int m = 8; m <= 16; m <<= 1) {
    f0 += __shfl_xor(f0, m); f1 += __shfl_xor(f1, m);
    f2 += __shfl_xor(f2, m); f3 += __shfl_xor(f3, m);
    f4 += __shfl_xor(f4, m); f5 += __shfl_xor(f5, m);
    f6 += __shfl_xor(f6, m); f7 += __shfl_xor(f7, m);
  }
  // elementwise epilogue: all lanes hold p2 for features sub*8+0..7 of node n
  float xt = x_tag[n];
  float s3f = (float)s3i[n] * 0x1p-23f;
  float4 w1a = *reinterpret_cast<const float4*>(&W1l[sub * 8]);
  float4 w1b = *reinterpret_cast<const float4*>(&W1l[sub * 8 + 4]);
  float4 w4a = *reinterpret_cast<const float4*>(&W4l[sub * 8]);
  float4 w4b = *reinterpret_cast<const float4*>(&W4l[sub * 8 + 4]);
  float o0 = fmaxf(fmaf(xt, w1a.x, fmaf(s3f, fmaxf(w4a.x, 0.f), f0)), 0.f);
  float o1 = fmaxf(fmaf(xt, w1a.y, fmaf(s3f, fmaxf(w4a.y, 0.f), f1)), 0.f);
  float o2 = fmaxf(fmaf(xt, w1a.z, fmaf(s3f, fmaxf(w4a.z, 0.f), f2)), 0.f);
  float o3 = fmaxf(fmaf(xt, w1a.w, fmaf(s3f, fmaxf(w4a.w, 0.f), f3)), 0.f);
  float o4 = fmaxf(fmaf(xt, w1b.x, fmaf(s3f, fmaxf(w4b.x, 0.f), f4)), 0.f);
  float o5 = fmaxf(fmaf(xt, w1b.y, fmaf(s3f, fmaxf(w4b.y, 0.f), f5)), 0.f);
  float o6 = fmaxf(fmaf(xt, w1b.z, fmaf(s3f, fmaxf(w4b.z, 0.f), f6)), 0.f);
  float o7 = fmaxf(fmaf(xt, w1b.w, fmaf(s3f, fmaxf(w4b.w, 0.f), f7)), 0.f);
  if (grp == 0) {
    uint4 o;
    o.x = (uint_t)f2b(o0) | ((uint_t)f2b(o1) << 16);
    o.y = (uint_t)f2b(o2) | ((uint_t)f2b(o3) << 16);
    o.z = (uint_t)f2b(o4) | ((uint_t)f2b(o5) << 16);
    o.w = (uint_t)f2b(o6) | ((uint_t)f2b(o7) << 16);
    *reinterpret_cast<uint4*>(&xout[(size_t)n * HID + sub * 8]) = o;
  }
}

// Last-layer head: t = x4@W7 (MFMA), Qr[n] = sum_h relu(t)*W5hi[h] via
// shfl reduce; block-reduced column sums flushed with one atomicAdd/feature.
__global__ __launch_bounds__(256) void qdense_kernel(
    const ushort_t* __restrict__ xin, const ushort_t* __restrict__ w7t,
    const float* __restrict__ w5hi, float* __restrict__ Qr,
    float* __restrict__ sumx) {
  __shared__ float ssum[4][HID];
  int tid = threadIdx.x;
  int lane = tid & 63;
  int wloc = tid >> 6;
  int wv = (blockIdx.x * blockDim.x + tid) >> 6;
  int n0 = wv * 16;
  bool valid = n0 < NN;
  int n0c = valid ? n0 : 0;
  int row = lane & 15;
  int g = lane >> 4;
  int ks = g * 8;
  bf16x8 a0 = *(const bf16x8*)&xin[(size_t)(n0c + row) * HID + ks];
  bf16x8 a1 = *(const bf16x8*)&xin[(size_t)(n0c + row) * HID + 32 + ks];
  float r0 = 0.f, r1 = 0.f, r2 = 0.f, r3 = 0.f;
  #pragma unroll
  for (int ct = 0; ct < 4; ++ct) {
    bf16x8 b0 = *(const bf16x8*)&w7t[(ct * 16 + row) * HID + ks];
    bf16x8 b1 = *(const bf16x8*)&w7t[(ct * 16 + row) * HID + 32 + ks];
    f32x4 acc = {0.f, 0.f, 0.f, 0.f};
    acc = __builtin_amdgcn_mfma_f32_16x16x32_bf16(a0, b0, acc, 0, 0, 0);
    acc = __builtin_amdgcn_mfma_f32_16x16x32_bf16(a1, b1, acc, 0, 0, 0);
    float w5 = w5hi[ct * 16 + row];
    r0 += fmaxf(acc[0], 0.f) * w5;
    r1 += fmaxf(acc[1], 0.f) * w5;
    r2 += fmaxf(acc[2], 0.f) * w5;
    r3 += fmaxf(acc[3], 0.f) * w5;
  }
  #pragma unroll
  for (int m = 1; m <= 8; m <<= 1) {
    r0 += __shfl_xor(r0, m); r1 += __shfl_xor(r1, m);
    r2 += __shfl_xor(r2, m); r3 += __shfl_xor(r3, m);
  }
  if (valid && row == 0) {
    int rb = n0 + g * 4;
    Qr[rb + 0] = r0; Qr[rb + 1] = r1; Qr[rb + 2] = r2; Qr[rb + 3] = r3;
  }
  float c[16];
  #pragma unroll
  for (int e = 0; e < 8; ++e) {
    c[e]     = valid ? b2f((ushort_t)a0[e]) : 0.f;
    c[8 + e] = valid ? b2f((ushort_t)a1[e]) : 0.f;
  }
  #pragma unroll
  for (int m = 1; m <= 8; m <<= 1) {
    #pragma unroll
    for (int e = 0; e < 16; ++e) c[e] += __shfl_xor(c[e], m);
  }
  if (row == 0) {
    #pragma unroll
    for (int e = 0; e < 8; ++e) {
      ssum[wloc][ks + e] = c[e];
      ssum[wloc][32 + ks + e] = c[8 + e];
    }
  }
  __syncthreads();
  if (tid < HID) {
    float s = ssum[0][tid] + ssum[1][tid] + ssum[2][tid] + ssum[3][tid];
    atomicAdd(&sumx[tid], s);
  }
}

// c0 = sum_h relu(sumx @ W6)[h] * W5[h]  — single wave.
__global__ void pool_kernel(const float* __restrict__ sumx, const float* __restrict__ W6,
                            const float* __restrict__ W5, float* __restrict__ c0) {
  int lane = threadIdx.x & 63;
  float sv = sumx[lane];
  float gp = 0.f;
  #pragma unroll
  for (int k = 0; k < HID; ++k) {
    float a = __int_as_float(__builtin_amdgcn_readlane(__float_as_int(sv), k));
    gp = fmaf(a, W6[k * HID + lane], gp);
  }
  float r = fmaxf(gp, 0.f) * W5[lane];
  #pragma unroll
  for (int m = 32; m >= 1; m >>= 1) r += __shfl_xor(r, m);
  if (lane == 0) *c0 = r;
}

// Q[n] += c0 (graph-pool constant).
__global__ void qfix_kernel(float* __restrict__ Q, const float* __restrict__ c0) {
  int i = blockIdx.x * blockDim.x + threadIdx.x;
  if (i < NN) Q[i] += *c0;
}

extern "C" void kernel_launch(void* const* d_in, const int* in_sizes, int n_in,
                              void* d_out, int out_size, void* d_ws, size_t ws_size,
                              hipStream_t stream) {
  const float* x         = (const float*)d_in[0];
  const float* x_tag     = (const float*)d_in[1];
  const float* edge_attr = (const float*)d_in[2];
  const int*   edge_index= (const int*)d_in[3];
  const float* W1        = (const float*)d_in[4];
  const float* W2        = (const float*)d_in[5];
  const float* W4        = (const float*)d_in[6];
  const float* W5        = (const float*)d_in[7];
  const float* W6        = (const float*)d_in[8];
  const float* W7        = (const float*)d_in[9];
  float* Q = (float*)d_out;

  const int QBLOCKS = ((NN / 16) * 64 + 255) / 256;   // 1563
  const int NTILES  = (NE + TILE_E - 1) / TILE_E;     // 1563

  char* ws = (char*)d_ws;
  size_t off = 0;
  auto alloc = [&](size_t bytes) -> void* {
    void* p = ws + off;
    off = (off + bytes + 255) & ~(size_t)255;
    return p;
  };
  // --- zeroed prefix ---
  int*      bincursor  = (int*)alloc(NBINS * 4);
  int*      bincursor2 = (int*)alloc(NBINS * 4);
  float*    sumx       = (float*)alloc(HID * 4);
  size_t zero_bytes = off;
  // --- no-zero region ---
  int*      s3i    = (int*)alloc(NN * 4);
  int*      cnt    = (int*)alloc(NN * 4);
  float*    c0     = (float*)alloc(4);
  ushort_t* xb0    = (ushort_t*)alloc((size_t)NN * HID * 2);
  ushort_t* xb1    = (ushort_t*)alloc((size_t)NN * HID * 2);
  ushort_t* ybuf   = (ushort_t*)alloc((size_t)(NN + 1) * HID * 2);  // +zero row
  ushort_t* w2t    = (ushort_t*)alloc((size_t)TL * HID * HID * 2);
  ushort_t* w7t    = (ushort_t*)alloc((size_t)HID * HID * 2);
  uint_t*   gbin   = (uint_t*)alloc((size_t)NBINS * BINCAP * 4);

  // Try to fit a second record buffer (merged edge pass); fall back if the
  // remaining colidx capacity would drop below 64 slots/node.
  size_t off_nog2 = off;
  uint_t* gbin2 = (uint_t*)alloc((size_t)NBINS * BINCAP * 4);
  bool merged = true;
  {
    size_t rem = (ws_size > off) ? (ws_size - off) : 0;
    if ((int)(rem / ((size_t)NN * 4)) < 64) { merged = false; off = off_nog2; }
  }
  size_t rem = (ws_size > off) ? (ws_size - off) : 0;
  int cap = (int)(rem / ((size_t)NN * 4));
  if (cap > 96) cap = 96;
  if (cap < 64) cap = 64;
  int* colidx = (int*)alloc((size_t)NN * cap * 4);

  hipMemsetAsync(d_ws, 0, zero_bytes, stream);
  hipMemsetAsync(ybuf + (size_t)NN * HID, 0, HID * 2, stream);  // sentinel row

  if (merged) {
    escatter_kernel<<<NTILES, 256, 0, stream>>>(edge_index, edge_attr,
                                                bincursor, gbin, bincursor2, gbin2);
    bucket_kernel<<<NBINS, 256, 0, stream>>>(gbin, bincursor, colidx, cnt, cap);
    s3bucket_kernel<<<NBINS, 256, 0, stream>>>(gbin2, bincursor2, s3i);
  } else {
    binscatter_kernel<<<NTILES, 256, 0, stream>>>(edge_index, bincursor, gbin);
    bucket_kernel<<<NBINS, 256, 0, stream>>>(gbin, bincursor, colidx, cnt, cap);
    sbinscatter_kernel<<<NTILES, 256, 0, stream>>>(edge_index, edge_attr, bincursor2, gbin);
    s3bucket_kernel<<<NBINS, 256, 0, stream>>>(gbin, bincursor2, s3i);
  }
  conv_kernel<<<(NN * HID / 4 + 255) / 256, 256, 0, stream>>>(x, xb0);
  wconv_kernel<<<((TL + 1) * HID * HID + 255) / 256, 256, 0, stream>>>(W2, W7, w2t, w7t);

  int ablocks = ((NN / 2) * 64 + 255) / 256;           // one wave per 2 nodes
  int dblocks = ((NN / 32) * 64 + 255) / 256;          // one wave per 32 nodes
  const ushort_t* xi = xb0;
  ushort_t* xo = xb1;
  for (int l = 0; l < TL; ++l) {
    dense_kernel<<<dblocks, 256, 0, stream>>>(xi, w2t + (size_t)l * HID * HID, ybuf);
    aggr_kernel<<<ablocks, 256, 0, stream>>>(ybuf, xo, cnt, colidx, cap,
                                             x_tag, s3i, W1 + l * HID, W4 + l * HID);
    ushort_t* tmp = (ushort_t*)xi;
    xi = xo;
    xo = (l == 0) ? xb0 : tmp;
  }

  qdense_kernel<<<QBLOCKS, 256, 0, stream>>>(xi, w7t, W5 + HID, Q, sumx);
  pool_kernel<<<1, 64, 0, stream>>>(sumx, W6, W5, c0);
  qfix_kernel<<<(NN + 255) / 256, 256, 0, stream>>>(Q, c0);
}

// Round 16
// 410.749 us; speedup vs baseline: 1.0562x; 1.0562x over previous
//
#include <hip/hip_runtime.h>

constexpr int NN  = 100000;    // nodes
constexpr int NE  = 3200000;   // edges
constexpr int HID = 64;
constexpr int TL  = 4;

constexpr int BIN_SHIFT = 9;                              // 512 nodes / bin
constexpr int BIN_NODES = 1 << BIN_SHIFT;
constexpr int NBINS     = (NN + BIN_NODES - 1) / BIN_NODES;  // 196
constexpr int BINCAP    = 18944;   // mean 16327 edges/bin, ~+20 sigma
constexpr int TILE_E    = 2048;    // edges per scatter tile (8/thread)
constexpr int PAD       = 48;      // padded neighbor-list length
constexpr int LROW      = 72;      // LDS row stride in ushorts (144 B)

typedef unsigned short ushort_t;
typedef unsigned int uint_t;
typedef __attribute__((ext_vector_type(8))) short bf16x8;   // MFMA A/B frag
typedef __attribute__((ext_vector_type(4))) float f32x4;    // MFMA C/D frag

__device__ __forceinline__ ushort_t f2b(float f) {       // fp32 -> bf16 RNE
  uint_t u = __float_as_uint(f);
  u += 0x7fff + ((u >> 16) & 1);
  return (ushort_t)(u >> 16);
}
__device__ __forceinline__ float b2f(ushort_t h) {
  return __uint_as_float(((uint_t)h) << 16);
}

// Merged edge pass with TILE-SORTED write-out (round-14 proven version).
__global__ __launch_bounds__(256) void escatter_kernel(
    const int* __restrict__ ei, const float* __restrict__ ea,
    int* __restrict__ bincursor, uint_t* __restrict__ gbin,
    int* __restrict__ bincursor2, uint_t* __restrict__ gbin2) {
  __shared__ int hist1[256], hist2[256];
  __shared__ int base1[NBINS], base2[NBINS];
  __shared__ int offs1[NBINS], offs2[NBINS];
  __shared__ int wt1[4], wt2[4];
  __shared__ uint_t srec[TILE_E];
  __shared__ int    sdst[TILE_E];
  int tid = threadIdx.x;
  int tb = blockIdx.x * TILE_E;
  hist1[tid] = 0; hist2[tid] = 0;
  __syncthreads();
  uint_t rec1[8], rec2[8]; int bn1[8], bn2[8], rk1[8], rk2[8];
  #pragma unroll
  for (int j = 0; j < 8; ++j) {
    int e = tb + tid + j * 256;
    bn1[j] = -1; bn2[j] = -1;
    rk1[j] = 0; rk2[j] = 0; rec1[j] = 0; rec2[j] = 0;
    if (e < NE) {
      int s = ei[e];
      int d = ei[NE + e];
      uint_t q = (uint_t)(int)(ea[e] * 8388608.0f);   // ea in [0,1): 23 bits
      bn1[j] = d >> BIN_SHIFT;
      rec1[j] = ((uint_t)s << BIN_SHIFT) | (uint_t)(d & (BIN_NODES - 1));
      rk1[j] = atomicAdd(&hist1[bn1[j]], 1);
      bn2[j] = s >> BIN_SHIFT;
      rec2[j] = (q << BIN_SHIFT) | (uint_t)(s & (BIN_NODES - 1));
      rk2[j] = atomicAdd(&hist2[bn2[j]], 1);
    }
  }
  __syncthreads();
  int c1 = hist1[tid], c2 = hist2[tid];
  int lane = tid & 63;
  int wvx = tid >> 6;
  int v1 = c1, v2 = c2;
  #pragma unroll
  for (int o = 1; o < 64; o <<= 1) {
    int t1 = __shfl_up(v1, o);
    int t2 = __shfl_up(v2, o);
    if (lane >= o) { v1 += t1; v2 += t2; }
  }
  if (lane == 63) { wt1[wvx] = v1; wt2[wvx] = v2; }
  __syncthreads();
  for (int k = 0; k < wvx; ++k) { v1 += wt1[k]; v2 += wt2[k]; }
  hist1[tid] = v1; hist2[tid] = v2;
  __syncthreads();
  if (tid < NBINS) {
    offs1[tid] = hist1[tid] - c1;
    offs2[tid] = hist2[tid] - c2;
    base1[tid] = c1 ? atomicAdd(&bincursor[tid], c1) : 0;
    base2[tid] = c2 ? atomicAdd(&bincursor2[tid], c2) : 0;
  }
  __syncthreads();
  int total1 = hist1[NBINS - 1];
  int total2 = hist2[NBINS - 1];
  #pragma unroll
  for (int j = 0; j < 8; ++j) {
    if (bn1[j] >= 0) {
      int p = offs1[bn1[j]] + rk1[j];
      int gp = base1[bn1[j]] + rk1[j];
      srec[p] = rec1[j];
      sdst[p] = (gp < BINCAP) ? (bn1[j] * BINCAP + gp) : -1;
    }
  }
  __syncthreads();
  for (int t = tid; t < total1; t += 256) {
    int g = sdst[t];
    if (g >= 0) gbin[g] = srec[t];
  }
  __syncthreads();
  #pragma unroll
  for (int j = 0; j < 8; ++j) {
    if (bn2[j] >= 0) {
      int p = offs2[bn2[j]] + rk2[j];
      int gp = base2[bn2[j]] + rk2[j];
      srec[p] = rec2[j];
      sdst[p] = (gp < BINCAP) ? (bn2[j] * BINCAP + gp) : -1;
    }
  }
  __syncthreads();
  for (int t = tid; t < total2; t += 256) {
    int g = sdst[t];
    if (g >= 0) gbin2[g] = srec[t];
  }
}

// K4: one block per bin; LDS cursors; scatter src into colidx.
// Pads slots [cur, PAD) with sentinel NN (zero row in y buffers).
__global__ __launch_bounds__(256) void bucket_kernel(
    const uint_t* __restrict__ gbin, const int* __restrict__ bincursor,
    int* __restrict__ colidx, int* __restrict__ cnt, int cap) {
  __shared__ int cur[BIN_NODES];
  int b = blockIdx.x;
  int tid = threadIdx.x;
  for (int i = tid; i < BIN_NODES; i += 256) cur[i] = 0;
  __syncthreads();
  int cb = min(bincursor[b], BINCAP);
  const uint_t* g = gbin + (size_t)b * BINCAP;
  for (int i = tid; i < cb; i += 256) {
    uint_t r = g[i];
    int dl = (int)(r & (BIN_NODES - 1));
    int src = (int)(r >> BIN_SHIFT);
    int pos = atomicAdd(&cur[dl], 1);
    int n = (b << BIN_SHIFT) + dl;
    if (pos < cap) colidx[(size_t)n * cap + pos] = src;
  }
  __syncthreads();
  for (int i = tid; i < BIN_NODES; i += 256) {
    int n = (b << BIN_SHIFT) + i;
    if (n < NN) cnt[n] = min(cur[i], cap);
  }
  for (int gsl = tid; gsl < BIN_NODES * 64; gsl += 256) {
    int i = gsl >> 6;
    int s = gsl & 63;
    int n = (b << BIN_SHIFT) + i;
    if (n < NN && s < PAD && s >= cur[i]) colidx[(size_t)n * cap + s] = NN;
  }
}

// K5b: one block per bin; 512-int LDS accumulator; coalesced s3i store.
__global__ __launch_bounds__(256) void s3bucket_kernel(
    const uint_t* __restrict__ gbin, const int* __restrict__ bincursor2,
    int* __restrict__ s3i) {
  __shared__ int acc[BIN_NODES];
  int b = blockIdx.x;
  int tid = threadIdx.x;
  for (int i = tid; i < BIN_NODES; i += 256) acc[i] = 0;
  __syncthreads();
  int cb = min(bincursor2[b], BINCAP);
  const uint_t* g = gbin + (size_t)b * BINCAP;
  for (int i = tid; i < cb; i += 256) {
    uint_t r = g[i];
    atomicAdd(&acc[r & (BIN_NODES - 1)], (int)(r >> BIN_SHIFT));
  }
  __syncthreads();
  for (int i = tid; i < BIN_NODES; i += 256) {
    int n = (b << BIN_SHIFT) + i;
    if (n < NN) s3i[n] = acc[i];
  }
}

// fp32 x -> bf16 (RNE), vectorized 4-wide.
__global__ void conv_kernel(const float* __restrict__ x, ushort_t* __restrict__ xb) {
  int i = blockIdx.x * blockDim.x + threadIdx.x;
  if (i * 4 >= NN * HID) return;
  const float4 v = *reinterpret_cast<const float4*>(&x[i * 4]);
  ushort4 o;
  o.x = f2b(v.x); o.y = f2b(v.y); o.z = f2b(v.z); o.w = f2b(v.w);
  *reinterpret_cast<ushort4*>(&xb[i * 4]) = o;
}

// W2 [l][k][h] fp32 -> W2T [l][h][k] bf16; W7 [k][h] -> W7T [h][k] bf16.
__global__ void wconv_kernel(const float* __restrict__ W2,
                             const float* __restrict__ W7,
                             ushort_t* __restrict__ w2t,
                             ushort_t* __restrict__ w7t) {
  int i = blockIdx.x * blockDim.x + threadIdx.x;
  int tot2 = TL * HID * HID;
  if (i < tot2) {
    int l = i >> 12, r = i & 4095, h = r >> 6, k = r & 63;
    w2t[i] = f2b(W2[(size_t)l * 4096 + k * 64 + h]);
  } else if (i < tot2 + HID * HID) {
    int j = i - tot2, h = j >> 6, k = j & 63;
    w7t[j] = f2b(W7[k * 64 + h]);
  }
}

// y = x @ W2 via MFMA (used once, layer 0). One wave = 32 nodes.
__global__ __launch_bounds__(256) void dense_kernel(
    const ushort_t* __restrict__ xin, const ushort_t* __restrict__ wt,
    ushort_t* __restrict__ yout) {
  int lane = threadIdx.x & 63;
  int wv = (blockIdx.x * blockDim.x + threadIdx.x) >> 6;
  int n0 = wv * 32;
  if (n0 >= NN) return;
  int row = lane & 15;
  int ks = (lane >> 4) * 8;
  bf16x8 a0 = *(const bf16x8*)&xin[(size_t)(n0 + row) * HID + ks];
  bf16x8 a1 = *(const bf16x8*)&xin[(size_t)(n0 + row) * HID + 32 + ks];
  bf16x8 a2 = *(const bf16x8*)&xin[(size_t)(n0 + 16 + row) * HID + ks];
  bf16x8 a3 = *(const bf16x8*)&xin[(size_t)(n0 + 16 + row) * HID + 32 + ks];
  #pragma unroll
  for (int ct = 0; ct < 4; ++ct) {
    bf16x8 b0 = *(const bf16x8*)&wt[(ct * 16 + row) * HID + ks];
    bf16x8 b1 = *(const bf16x8*)&wt[(ct * 16 + row) * HID + 32 + ks];
    f32x4 acc0 = {0.f, 0.f, 0.f, 0.f};
    f32x4 acc1 = {0.f, 0.f, 0.f, 0.f};
    acc0 = __builtin_amdgcn_mfma_f32_16x16x32_bf16(a0, b0, acc0, 0, 0, 0);
    acc0 = __builtin_amdgcn_mfma_f32_16x16x32_bf16(a1, b1, acc0, 0, 0, 0);
    acc1 = __builtin_amdgcn_mfma_f32_16x16x32_bf16(a2, b0, acc1, 0, 0, 0);
    acc1 = __builtin_amdgcn_mfma_f32_16x16x32_bf16(a3, b1, acc1, 0, 0, 0);
    int rr = (lane >> 4) * 4;
    #pragma unroll
    for (int r = 0; r < 4; ++r) {
      yout[(size_t)(n0 + rr + r) * HID + ct * 16 + row] = f2b(acc0[r]);
      yout[(size_t)(n0 + 16 + rr + r) * HID + ct * 16 + row] = f2b(acc1[r]);
    }
  }
}

// FUSED layer kernel: gather-sum of y rows + elementwise epilogue + (unless
// last layer) x_new @ W2_next via block MFMA -> writes y_next directly.
// 512 threads = 8 waves = 16 nodes/block. Gather: 2 nodes/wave (r14 path).
// x_new staged in a 16x64 LDS tile (144 B row stride, 2-way bank-free);
// waves 0..3 each compute one 16-col MFMA tile. Last layer (w2tn==null)
// writes x_new to global for the Q head instead.
__global__ __launch_bounds__(512) void aggrf_kernel(
    const ushort_t* __restrict__ yin, ushort_t* __restrict__ out,
    const ushort_t* __restrict__ w2tn,
    const int* __restrict__ cnt, const int* __restrict__ colidx, int cap,
    const float* __restrict__ x_tag, const int* __restrict__ s3i,
    const float* __restrict__ W1l, const float* __restrict__ W4l) {
  __shared__ ushort_t sx[16 * LROW];
  int tid = threadIdx.x;
  int lane = tid & 63;
  int wv = tid >> 6;                     // 0..7
  int n0b = blockIdx.x * 16;
  int half = lane >> 5;                  // node select within wave
  int nloc = wv * 2 + half;              // 0..15
  int n = n0b + nloc;                    // NN = 6250*16 exactly
  int grp = (lane >> 3) & 3;             // 4 row-groups of 8 lanes
  int sub = lane & 7;
  const int* cl = colidx + (size_t)n * cap + grp;
  float f0 = 0.f, f1 = 0.f, f2 = 0.f, f3 = 0.f;
  float f4 = 0.f, f5 = 0.f, f6 = 0.f, f7 = 0.f;
  uint4 w[12];
  #pragma unroll
  for (int j = 0; j < 12; ++j) {
    int c = cl[j * 4];
    w[j] = *reinterpret_cast<const uint4*>(&yin[(size_t)c * HID + sub * 8]);
  }
  #pragma unroll
  for (int j = 0; j < 12; ++j) {
    f0 += __uint_as_float(w[j].x << 16);
    f1 += __uint_as_float(w[j].x & 0xffff0000u);
    f2 += __uint_as_float(w[j].y << 16);
    f3 += __uint_as_float(w[j].y & 0xffff0000u);
    f4 += __uint_as_float(w[j].z << 16);
    f5 += __uint_as_float(w[j].z & 0xffff0000u);
    f6 += __uint_as_float(w[j].w << 16);
    f7 += __uint_as_float(w[j].w & 0xffff0000u);
  }
  int deg = cnt[n];
  if (__any(deg > PAD)) {                // rare tail (cap<=96)
    int t2 = deg - PAD;
    const int* ct2 = colidx + (size_t)n * cap + PAD;
    for (int jt = 0; jt < 12; ++jt) {
      int idx = jt * 4 + grp;
      if (idx < t2) {
        int c = ct2[idx];
        uint4 ww = *reinterpret_cast<const uint4*>(&yin[(size_t)c * HID + sub * 8]);
        f0 += __uint_as_float(ww.x << 16);
        f1 += __uint_as_float(ww.x & 0xffff0000u);
        f2 += __uint_as_float(ww.y << 16);
        f3 += __uint_as_float(ww.y & 0xffff0000u);
        f4 += __uint_as_float(ww.z << 16);
        f5 += __uint_as_float(ww.z & 0xffff0000u);
        f6 += __uint_as_float(ww.w << 16);
        f7 += __uint_as_float(ww.w & 0xffff0000u);
      }
    }
  }
  #pragma unroll
  for (int m = 8; m <= 16; m <<= 1) {
    f0 += __shfl_xor(f0, m); f1 += __shfl_xor(f1, m);
    f2 += __shfl_xor(f2, m); f3 += __shfl_xor(f3, m);
    f4 += __shfl_xor(f4, m); f5 += __shfl_xor(f5, m);
    f6 += __shfl_xor(f6, m); f7 += __shfl_xor(f7, m);
  }
  float xt = x_tag[n];
  float s3f = (float)s3i[n] * 0x1p-23f;
  float4 w1a = *reinterpret_cast<const float4*>(&W1l[sub * 8]);
  float4 w1b = *reinterpret_cast<const float4*>(&W1l[sub * 8 + 4]);
  float4 w4a = *reinterpret_cast<const float4*>(&W4l[sub * 8]);
  float4 w4b = *reinterpret_cast<const float4*>(&W4l[sub * 8 + 4]);
  float o0 = fmaxf(fmaf(xt, w1a.x, fmaf(s3f, fmaxf(w4a.x, 0.f), f0)), 0.f);
  float o1 = fmaxf(fmaf(xt, w1a.y, fmaf(s3f, fmaxf(w4a.y, 0.f), f1)), 0.f);
  float o2 = fmaxf(fmaf(xt, w1a.z, fmaf(s3f, fmaxf(w4a.z, 0.f), f2)), 0.f);
  float o3 = fmaxf(fmaf(xt, w1a.w, fmaf(s3f, fmaxf(w4a.w, 0.f), f3)), 0.f);
  float o4 = fmaxf(fmaf(xt, w1b.x, fmaf(s3f, fmaxf(w4b.x, 0.f), f4)), 0.f);
  float o5 = fmaxf(fmaf(xt, w1b.y, fmaf(s3f, fmaxf(w4b.y, 0.f), f5)), 0.f);
  float o6 = fmaxf(fmaf(xt, w1b.z, fmaf(s3f, fmaxf(w4b.z, 0.f), f6)), 0.f);
  float o7 = fmaxf(fmaf(xt, w1b.w, fmaf(s3f, fmaxf(w4b.w, 0.f), f7)), 0.f);
  uint4 o;
  o.x = (uint_t)f2b(o0) | ((uint_t)f2b(o1) << 16);
  o.y = (uint_t)f2b(o2) | ((uint_t)f2b(o3) << 16);
  o.z = (uint_t)f2b(o4) | ((uint_t)f2b(o5) << 16);
  o.w = (uint_t)f2b(o6) | ((uint_t)f2b(o7) << 16);
  if (w2tn) {
    // stage x_new into LDS, then fused dense for the NEXT layer
    if (grp == 0)
      *reinterpret_cast<uint4*>(&sx[nloc * LROW + sub * 8]) = o;
    __syncthreads();
    if (wv < 4) {
      int row = lane & 15;
      int ks = (lane >> 4) * 8;
      bf16x8 a0 = *(const bf16x8*)&sx[row * LROW + ks];
      bf16x8 a1 = *(const bf16x8*)&sx[row * LROW + 32 + ks];
      int ct = wv;
      bf16x8 b0 = *(const bf16x8*)&w2tn[(ct * 16 + row) * HID + ks];
      bf16x8 b1 = *(const bf16x8*)&w2tn[(ct * 16 + row) * HID + 32 + ks];
      f32x4 acc = {0.f, 0.f, 0.f, 0.f};
      acc = __builtin_amdgcn_mfma_f32_16x16x32_bf16(a0, b0, acc, 0, 0, 0);
      acc = __builtin_amdgcn_mfma_f32_16x16x32_bf16(a1, b1, acc, 0, 0, 0);
      int rr = (lane >> 4) * 4;
      #pragma unroll
      for (int r = 0; r < 4; ++r)
        out[(size_t)(n0b + rr + r) * HID + ct * 16 + row] = f2b(acc[r]);
    }
  } else {
    // last layer: write x_new to global for the Q head
    if (grp == 0)
      *reinterpret_cast<uint4*>(&out[(size_t)n * HID + sub * 8]) = o;
  }
}

// Last-layer head: t = x4@W7 (MFMA), Qr[n] = sum_h relu(t)*W5hi[h] via
// shfl reduce; block-reduced column sums flushed with one atomicAdd/feature.
__global__ __launch_bounds__(256) void qdense_kernel(
    const ushort_t* __restrict__ xin, const ushort_t* __restrict__ w7t,
    const float* __restrict__ w5hi, float* __restrict__ Qr,
    float* __restrict__ sumx) {
  __shared__ float ssum[4][HID];
  int tid = threadIdx.x;
  int lane = tid & 63;
  int wloc = tid >> 6;
  int wv = (blockIdx.x * blockDim.x + tid) >> 6;
  int n0 = wv * 16;
  bool valid = n0 < NN;
  int n0c = valid ? n0 : 0;
  int row = lane & 15;
  int g = lane >> 4;
  int ks = g * 8;
  bf16x8 a0 = *(const bf16x8*)&xin[(size_t)(n0c + row) * HID + ks];
  bf16x8 a1 = *(const bf16x8*)&xin[(size_t)(n0c + row) * HID + 32 + ks];
  float r0 = 0.f, r1 = 0.f, r2 = 0.f, r3 = 0.f;
  #pragma unroll
  for (int ct = 0; ct < 4; ++ct) {
    bf16x8 b0 = *(const bf16x8*)&w7t[(ct * 16 + row) * HID + ks];
    bf16x8 b1 = *(const bf16x8*)&w7t[(ct * 16 + row) * HID + 32 + ks];
    f32x4 acc = {0.f, 0.f, 0.f, 0.f};
    acc = __builtin_amdgcn_mfma_f32_16x16x32_bf16(a0, b0, acc, 0, 0, 0);
    acc = __builtin_amdgcn_mfma_f32_16x16x32_bf16(a1, b1, acc, 0, 0, 0);
    float w5 = w5hi[ct * 16 + row];
    r0 += fmaxf(acc[0], 0.f) * w5;
    r1 += fmaxf(acc[1], 0.f) * w5;
    r2 += fmaxf(acc[2], 0.f) * w5;
    r3 += fmaxf(acc[3], 0.f) * w5;
  }
  #pragma unroll
  for (int m = 1; m <= 8; m <<= 1) {
    r0 += __shfl_xor(r0, m); r1 += __shfl_xor(r1, m);
    r2 += __shfl_xor(r2, m); r3 += __shfl_xor(r3, m);
  }
  if (valid && row == 0) {
    int rb = n0 + g * 4;
    Qr[rb + 0] = r0; Qr[rb + 1] = r1; Qr[rb + 2] = r2; Qr[rb + 3] = r3;
  }
  float c[16];
  #pragma unroll
  for (int e = 0; e < 8; ++e) {
    c[e]     = valid ? b2f((ushort_t)a0[e]) : 0.f;
    c[8 + e] = valid ? b2f((ushort_t)a1[e]) : 0.f;
  }
  #pragma unroll
  for (int m = 1; m <= 8; m <<= 1) {
    #pragma unroll
    for (int e = 0; e < 16; ++e) c[e] += __shfl_xor(c[e], m);
  }
  if (row == 0) {
    #pragma unroll
    for (int e = 0; e < 8; ++e) {
      ssum[wloc][ks + e] = c[e];
      ssum[wloc][32 + ks + e] = c[8 + e];
    }
  }
  __syncthreads();
  if (tid < HID) {
    float s = ssum[0][tid] + ssum[1][tid] + ssum[2][tid] + ssum[3][tid];
    atomicAdd(&sumx[tid], s);
  }
}

// c0 = sum_h relu(sumx @ W6)[h] * W5[h]  — single wave.
__global__ void pool_kernel(const float* __restrict__ sumx, const float* __restrict__ W6,
                            const float* __restrict__ W5, float* __restrict__ c0) {
  int lane = threadIdx.x & 63;
  float sv = sumx[lane];
  float gp = 0.f;
  #pragma unroll
  for (int k = 0; k < HID; ++k) {
    float a = __int_as_float(__builtin_amdgcn_readlane(__float_as_int(sv), k));
    gp = fmaf(a, W6[k * HID + lane], gp);
  }
  float r = fmaxf(gp, 0.f) * W5[lane];
  #pragma unroll
  for (int m = 32; m >= 1; m >>= 1) r += __shfl_xor(r, m);
  if (lane == 0) *c0 = r;
}

// Q[n] += c0 (graph-pool constant).
__global__ void qfix_kernel(float* __restrict__ Q, const float* __restrict__ c0) {
  int i = blockIdx.x * blockDim.x + threadIdx.x;
  if (i < NN) Q[i] += *c0;
}

extern "C" void kernel_launch(void* const* d_in, const int* in_sizes, int n_in,
                              void* d_out, int out_size, void* d_ws, size_t ws_size,
                              hipStream_t stream) {
  const float* x         = (const float*)d_in[0];
  const float* x_tag     = (const float*)d_in[1];
  const float* edge_attr = (const float*)d_in[2];
  const int*   edge_index= (const int*)d_in[3];
  const float* W1        = (const float*)d_in[4];
  const float* W2        = (const float*)d_in[5];
  const float* W4        = (const float*)d_in[6];
  const float* W5        = (const float*)d_in[7];
  const float* W6        = (const float*)d_in[8];
  const float* W7        = (const float*)d_in[9];
  float* Q = (float*)d_out;

  const int QBLOCKS = ((NN / 16) * 64 + 255) / 256;   // 1563
  const int NTILES  = (NE + TILE_E - 1) / TILE_E;     // 1563

  char* ws = (char*)d_ws;
  size_t off = 0;
  auto alloc = [&](size_t bytes) -> void* {
    void* p = ws + off;
    off = (off + bytes + 255) & ~(size_t)255;
    return p;
  };
  // --- zeroed prefix ---
  int*      bincursor  = (int*)alloc(NBINS * 4);
  int*      bincursor2 = (int*)alloc(NBINS * 4);
  float*    sumx       = (float*)alloc(HID * 4);
  size_t zero_bytes = off;
  // --- no-zero region ---
  int*      s3i    = (int*)alloc(NN * 4);
  int*      cnt    = (int*)alloc(NN * 4);
  float*    c0     = (float*)alloc(4);
  ushort_t* xf     = (ushort_t*)alloc((size_t)NN * HID * 2);      // bf16 x (in/out)
  ushort_t* yb0    = (ushort_t*)alloc((size_t)(NN + 1) * HID * 2); // +zero row
  ushort_t* yb1    = (ushort_t*)alloc((size_t)(NN + 1) * HID * 2); // +zero row
  ushort_t* w2t    = (ushort_t*)alloc((size_t)TL * HID * HID * 2);
  ushort_t* w7t    = (ushort_t*)alloc((size_t)HID * HID * 2);
  uint_t*   gbin   = (uint_t*)alloc((size_t)NBINS * BINCAP * 4);
  uint_t*   gbin2  = (uint_t*)alloc((size_t)NBINS * BINCAP * 4);

  size_t rem = (ws_size > off) ? (ws_size - off) : 0;
  int cap = (int)(rem / ((size_t)NN * 4));
  if (cap > 96) cap = 96;
  if (cap < 64) cap = 64;
  int* colidx = (int*)alloc((size_t)NN * cap * 4);

  hipMemsetAsync(d_ws, 0, zero_bytes, stream);
  hipMemsetAsync(yb0 + (size_t)NN * HID, 0, HID * 2, stream);  // sentinel rows
  hipMemsetAsync(yb1 + (size_t)NN * HID, 0, HID * 2, stream);

  escatter_kernel<<<NTILES, 256, 0, stream>>>(edge_index, edge_attr,
                                              bincursor, gbin, bincursor2, gbin2);
  bucket_kernel<<<NBINS, 256, 0, stream>>>(gbin, bincursor, colidx, cnt, cap);
  s3bucket_kernel<<<NBINS, 256, 0, stream>>>(gbin2, bincursor2, s3i);
  conv_kernel<<<(NN * HID / 4 + 255) / 256, 256, 0, stream>>>(x, xf);
  wconv_kernel<<<((TL + 1) * HID * HID + 255) / 256, 256, 0, stream>>>(W2, W7, w2t, w7t);

  int dblocks = ((NN / 32) * 64 + 255) / 256;
  dense_kernel<<<dblocks, 256, 0, stream>>>(xf, w2t, yb0);   // y for layer 0

  int fblocks = NN / 16;                                      // 6250
  ushort_t* ycur = yb0;
  ushort_t* ynext = yb1;
  for (int l = 0; l < TL; ++l) {
    bool last = (l == TL - 1);
    aggrf_kernel<<<fblocks, 512, 0, stream>>>(
        ycur, last ? xf : ynext,
        last ? nullptr : (w2t + (size_t)(l + 1) * HID * HID),
        cnt, colidx, cap, x_tag, s3i, W1 + l * HID, W4 + l * HID);
    ushort_t* t = ycur; ycur = ynext; ynext = t;
  }

  qdense_kernel<<<QBLOCKS, 256, 0, stream>>>(xf, w7t, W5 + HID, Q, sumx);
  pool_kernel<<<1, 64, 0, stream>>>(sumx, W6, W5, c0);
  qfix_kernel<<<(NN + 255) / 256, 256, 0, stream>>>(Q, c0);
}

// Round 17
// 394.979 us; speedup vs baseline: 1.0983x; 1.0399x over previous
//
#include <hip/hip_runtime.h>

constexpr int NN  = 100000;    // nodes
constexpr int NE  = 3200000;   // edges
constexpr int HID = 64;
constexpr int TL  = 4;

constexpr int BIN_SHIFT = 9;                              // 512 nodes / bin
constexpr int BIN_NODES = 1 << BIN_SHIFT;
constexpr int NBINS     = (NN + BIN_NODES - 1) / BIN_NODES;  // 196
constexpr int BINCAP    = 18944;   // mean 16327 edges/bin, ~+20 sigma
constexpr int TILE_E    = 4096;    // edges per scatter tile (16/thread)
constexpr int PAD       = 48;      // padded neighbor-list length
constexpr int LROW      = 72;      // LDS row stride in ushorts (144 B)

typedef unsigned short ushort_t;
typedef unsigned int uint_t;
typedef unsigned char uchar_t;
typedef __attribute__((ext_vector_type(8))) short bf16x8;   // MFMA A/B frag
typedef __attribute__((ext_vector_type(4))) float f32x4;    // MFMA C/D frag

__device__ __forceinline__ ushort_t f2b(float f) {       // fp32 -> bf16 RNE
  uint_t u = __float_as_uint(f);
  u += 0x7fff + ((u >> 16) & 1);
  return (ushort_t)(u >> 16);
}
__device__ __forceinline__ float b2f(ushort_t h) {
  return __uint_as_float(((uint_t)h) << 16);
}

// Merged edge pass, tile-sorted write-out, 4096-edge tiles (long write runs).
// The two record streams share one LDS staging set and run sequentially;
// stream 2 re-reads ei/ea (L2-hot). Meta packed (bn<<12)|rk per record.
__global__ __launch_bounds__(256) void escatter_kernel(
    const int* __restrict__ ei, const float* __restrict__ ea,
    int* __restrict__ bincursor, uint_t* __restrict__ gbin,
    int* __restrict__ bincursor2, uint_t* __restrict__ gbin2) {
  __shared__ int hist[256];
  __shared__ int base[NBINS], offs[NBINS];
  __shared__ int wt[4];
  __shared__ uint_t  srec[TILE_E];
  __shared__ uchar_t sbin[TILE_E];
  int tid = threadIdx.x;
  int tb = blockIdx.x * TILE_E;
  int lane = tid & 63;
  int wvx = tid >> 6;

  for (int stream = 0; stream < 2; ++stream) {
    hist[tid] = 0;
    __syncthreads();
    uint_t rec[16]; int meta[16];          // meta = (bn<<12)|rk, -1 if dead
    #pragma unroll
    for (int j = 0; j < 16; ++j) {
      int e = tb + tid + j * 256;
      meta[j] = -1; rec[j] = 0;
      if (e < NE) {
        int s = ei[e];
        int bn, lo; uint_t hi;
        if (stream == 0) {
          int d = ei[NE + e];
          bn = d >> BIN_SHIFT; lo = d & (BIN_NODES - 1);
          hi = (uint_t)s;
        } else {
          bn = s >> BIN_SHIFT; lo = s & (BIN_NODES - 1);
          hi = (uint_t)(int)(ea[e] * 8388608.0f);   // ea in [0,1): 23 bits
        }
        rec[j] = (hi << BIN_SHIFT) | (uint_t)lo;
        int rk = atomicAdd(&hist[bn], 1);
        meta[j] = (bn << 12) | rk;
      }
    }
    __syncthreads();
    int c = hist[tid];
    // inclusive scan: per-wave shfl + cross-wave combine
    int v = c;
    #pragma unroll
    for (int o = 1; o < 64; o <<= 1) {
      int t = __shfl_up(v, o);
      if (lane >= o) v += t;
    }
    if (lane == 63) wt[wvx] = v;
    __syncthreads();
    for (int k = 0; k < wvx; ++k) v += wt[k];
    hist[tid] = v;                          // inclusive totals
    if (tid < NBINS) {
      offs[tid] = v - c;
      int* cur = stream ? bincursor2 : bincursor;
      base[tid] = c ? atomicAdd(&cur[tid], c) : 0;
    }
    __syncthreads();
    int total = hist[NBINS - 1];
    #pragma unroll
    for (int j = 0; j < 16; ++j) {
      if (meta[j] >= 0) {
        int bn = meta[j] >> 12, rk = meta[j] & 4095;
        int p = offs[bn] + rk;
        srec[p] = rec[j];
        sbin[p] = (uchar_t)bn;
      }
    }
    __syncthreads();
    uint_t* g = stream ? gbin2 : gbin;
    for (int t = tid; t < total; t += 256) {
      int b = sbin[t];
      int gp = base[b] + (t - offs[b]);
      if (gp < BINCAP) g[(size_t)b * BINCAP + gp] = srec[t];
    }
    __syncthreads();
  }
}

// K4: one block per bin; LDS cursors; scatter src into colidx.
// Pads slots [cur, PAD) with sentinel NN (zero row in y buffers).
__global__ __launch_bounds__(256) void bucket_kernel(
    const uint_t* __restrict__ gbin, const int* __restrict__ bincursor,
    int* __restrict__ colidx, int* __restrict__ cnt, int cap) {
  __shared__ int cur[BIN_NODES];
  int b = blockIdx.x;
  int tid = threadIdx.x;
  for (int i = tid; i < BIN_NODES; i += 256) cur[i] = 0;
  __syncthreads();
  int cb = min(bincursor[b], BINCAP);
  const uint_t* g = gbin + (size_t)b * BINCAP;
  for (int i = tid; i < cb; i += 256) {
    uint_t r = g[i];
    int dl = (int)(r & (BIN_NODES - 1));
    int src = (int)(r >> BIN_SHIFT);
    int pos = atomicAdd(&cur[dl], 1);
    int n = (b << BIN_SHIFT) + dl;
    if (pos < cap) colidx[(size_t)n * cap + pos] = src;
  }
  __syncthreads();
  for (int i = tid; i < BIN_NODES; i += 256) {
    int n = (b << BIN_SHIFT) + i;
    if (n < NN) cnt[n] = min(cur[i], cap);
  }
  for (int gsl = tid; gsl < BIN_NODES * 64; gsl += 256) {
    int i = gsl >> 6;
    int s = gsl & 63;
    int n = (b << BIN_SHIFT) + i;
    if (n < NN && s < PAD && s >= cur[i]) colidx[(size_t)n * cap + s] = NN;
  }
}

// K5b: one block per bin; 512-int LDS accumulator; coalesced s3i store.
__global__ __launch_bounds__(256) void s3bucket_kernel(
    const uint_t* __restrict__ gbin, const int* __restrict__ bincursor2,
    int* __restrict__ s3i) {
  __shared__ int acc[BIN_NODES];
  int b = blockIdx.x;
  int tid = threadIdx.x;
  for (int i = tid; i < BIN_NODES; i += 256) acc[i] = 0;
  __syncthreads();
  int cb = min(bincursor2[b], BINCAP);
  const uint_t* g = gbin + (size_t)b * BINCAP;
  for (int i = tid; i < cb; i += 256) {
    uint_t r = g[i];
    atomicAdd(&acc[r & (BIN_NODES - 1)], (int)(r >> BIN_SHIFT));
  }
  __syncthreads();
  for (int i = tid; i < BIN_NODES; i += 256) {
    int n = (b << BIN_SHIFT) + i;
    if (n < NN) s3i[n] = acc[i];
  }
}

// W2 [l][k][h] fp32 -> W2T [l][h][k] bf16; W7 [k][h] -> W7T [h][k] bf16.
__global__ void wconv_kernel(const float* __restrict__ W2,
                             const float* __restrict__ W7,
                             ushort_t* __restrict__ w2t,
                             ushort_t* __restrict__ w7t) {
  int i = blockIdx.x * blockDim.x + threadIdx.x;
  int tot2 = TL * HID * HID;
  if (i < tot2) {
    int l = i >> 12, r = i & 4095, h = r >> 6, k = r & 63;
    w2t[i] = f2b(W2[(size_t)l * 4096 + k * 64 + h]);
  } else if (i < tot2 + HID * HID) {
    int j = i - tot2, h = j >> 6, k = j & 63;
    w7t[j] = f2b(W7[k * 64 + h]);
  }
}

__device__ __forceinline__ bf16x8 ld8f(const float* p) {  // 8 fp32 -> bf16x8
  float4 u = *reinterpret_cast<const float4*>(p);
  float4 v = *reinterpret_cast<const float4*>(p + 4);
  bf16x8 r;
  r[0] = (short)f2b(u.x); r[1] = (short)f2b(u.y);
  r[2] = (short)f2b(u.z); r[3] = (short)f2b(u.w);
  r[4] = (short)f2b(v.x); r[5] = (short)f2b(v.y);
  r[6] = (short)f2b(v.z); r[7] = (short)f2b(v.w);
  return r;
}

// y0 = x @ W2[0] via MFMA, reading fp32 x with inline bf16 conversion
// (conv_kernel eliminated). One wave = 32 nodes.
__global__ __launch_bounds__(256) void dense_kernel(
    const float* __restrict__ xin, const ushort_t* __restrict__ wt,
    ushort_t* __restrict__ yout) {
  int lane = threadIdx.x & 63;
  int wv = (blockIdx.x * blockDim.x + threadIdx.x) >> 6;
  int n0 = wv * 32;
  if (n0 >= NN) return;
  int row = lane & 15;
  int ks = (lane >> 4) * 8;
  bf16x8 a0 = ld8f(&xin[(size_t)(n0 + row) * HID + ks]);
  bf16x8 a1 = ld8f(&xin[(size_t)(n0 + row) * HID + 32 + ks]);
  bf16x8 a2 = ld8f(&xin[(size_t)(n0 + 16 + row) * HID + ks]);
  bf16x8 a3 = ld8f(&xin[(size_t)(n0 + 16 + row) * HID + 32 + ks]);
  #pragma unroll
  for (int ct = 0; ct < 4; ++ct) {
    bf16x8 b0 = *(const bf16x8*)&wt[(ct * 16 + row) * HID + ks];
    bf16x8 b1 = *(const bf16x8*)&wt[(ct * 16 + row) * HID + 32 + ks];
    f32x4 acc0 = {0.f, 0.f, 0.f, 0.f};
    f32x4 acc1 = {0.f, 0.f, 0.f, 0.f};
    acc0 = __builtin_amdgcn_mfma_f32_16x16x32_bf16(a0, b0, acc0, 0, 0, 0);
    acc0 = __builtin_amdgcn_mfma_f32_16x16x32_bf16(a1, b1, acc0, 0, 0, 0);
    acc1 = __builtin_amdgcn_mfma_f32_16x16x32_bf16(a2, b0, acc1, 0, 0, 0);
    acc1 = __builtin_amdgcn_mfma_f32_16x16x32_bf16(a3, b1, acc1, 0, 0, 0);
    int rr = (lane >> 4) * 4;
    #pragma unroll
    for (int r = 0; r < 4; ++r) {
      yout[(size_t)(n0 + rr + r) * HID + ct * 16 + row] = f2b(acc0[r]);
      yout[(size_t)(n0 + 16 + rr + r) * HID + ct * 16 + row] = f2b(acc1[r]);
    }
  }
}

// FUSED layer kernel (round-16 proven): gather-sum + epilogue + next-layer
// dense via block MFMA. 512 threads = 16 nodes/block.
__global__ __launch_bounds__(512) void aggrf_kernel(
    const ushort_t* __restrict__ yin, ushort_t* __restrict__ out,
    const ushort_t* __restrict__ w2tn,
    const int* __restrict__ cnt, const int* __restrict__ colidx, int cap,
    const float* __restrict__ x_tag, const int* __restrict__ s3i,
    const float* __restrict__ W1l, const float* __restrict__ W4l) {
  __shared__ ushort_t sx[16 * LROW];
  int tid = threadIdx.x;
  int lane = tid & 63;
  int wv = tid >> 6;                     // 0..7
  int n0b = blockIdx.x * 16;
  int half = lane >> 5;
  int nloc = wv * 2 + half;              // 0..15
  int n = n0b + nloc;                    // NN = 6250*16 exactly
  int grp = (lane >> 3) & 3;
  int sub = lane & 7;
  const int* cl = colidx + (size_t)n * cap + grp;
  float f0 = 0.f, f1 = 0.f, f2 = 0.f, f3 = 0.f;
  float f4 = 0.f, f5 = 0.f, f6 = 0.f, f7 = 0.f;
  uint4 w[12];
  #pragma unroll
  for (int j = 0; j < 12; ++j) {
    int c = cl[j * 4];
    w[j] = *reinterpret_cast<const uint4*>(&yin[(size_t)c * HID + sub * 8]);
  }
  #pragma unroll
  for (int j = 0; j < 12; ++j) {
    f0 += __uint_as_float(w[j].x << 16);
    f1 += __uint_as_float(w[j].x & 0xffff0000u);
    f2 += __uint_as_float(w[j].y << 16);
    f3 += __uint_as_float(w[j].y & 0xffff0000u);
    f4 += __uint_as_float(w[j].z << 16);
    f5 += __uint_as_float(w[j].z & 0xffff0000u);
    f6 += __uint_as_float(w[j].w << 16);
    f7 += __uint_as_float(w[j].w & 0xffff0000u);
  }
  int deg = cnt[n];
  if (__any(deg > PAD)) {                // rare tail (cap<=96)
    int t2 = deg - PAD;
    const int* ct2 = colidx + (size_t)n * cap + PAD;
    for (int jt = 0; jt < 12; ++jt) {
      int idx = jt * 4 + grp;
      if (idx < t2) {
        int c = ct2[idx];
        uint4 ww = *reinterpret_cast<const uint4*>(&yin[(size_t)c * HID + sub * 8]);
        f0 += __uint_as_float(ww.x << 16);
        f1 += __uint_as_float(ww.x & 0xffff0000u);
        f2 += __uint_as_float(ww.y << 16);
        f3 += __uint_as_float(ww.y & 0xffff0000u);
        f4 += __uint_as_float(ww.z << 16);
        f5 += __uint_as_float(ww.z & 0xffff0000u);
        f6 += __uint_as_float(ww.w << 16);
        f7 += __uint_as_float(ww.w & 0xffff0000u);
      }
    }
  }
  #pragma unroll
  for (int m = 8; m <= 16; m <<= 1) {
    f0 += __shfl_xor(f0, m); f1 += __shfl_xor(f1, m);
    f2 += __shfl_xor(f2, m); f3 += __shfl_xor(f3, m);
    f4 += __shfl_xor(f4, m); f5 += __shfl_xor(f5, m);
    f6 += __shfl_xor(f6, m); f7 += __shfl_xor(f7, m);
  }
  float xt = x_tag[n];
  float s3f = (float)s3i[n] * 0x1p-23f;
  float4 w1a = *reinterpret_cast<const float4*>(&W1l[sub * 8]);
  float4 w1b = *reinterpret_cast<const float4*>(&W1l[sub * 8 + 4]);
  float4 w4a = *reinterpret_cast<const float4*>(&W4l[sub * 8]);
  float4 w4b = *reinterpret_cast<const float4*>(&W4l[sub * 8 + 4]);
  float o0 = fmaxf(fmaf(xt, w1a.x, fmaf(s3f, fmaxf(w4a.x, 0.f), f0)), 0.f);
  float o1 = fmaxf(fmaf(xt, w1a.y, fmaf(s3f, fmaxf(w4a.y, 0.f), f1)), 0.f);
  float o2 = fmaxf(fmaf(xt, w1a.z, fmaf(s3f, fmaxf(w4a.z, 0.f), f2)), 0.f);
  float o3 = fmaxf(fmaf(xt, w1a.w, fmaf(s3f, fmaxf(w4a.w, 0.f), f3)), 0.f);
  float o4 = fmaxf(fmaf(xt, w1b.x, fmaf(s3f, fmaxf(w4b.x, 0.f), f4)), 0.f);
  float o5 = fmaxf(fmaf(xt, w1b.y, fmaf(s3f, fmaxf(w4b.y, 0.f), f5)), 0.f);
  float o6 = fmaxf(fmaf(xt, w1b.z, fmaf(s3f, fmaxf(w4b.z, 0.f), f6)), 0.f);
  float o7 = fmaxf(fmaf(xt, w1b.w, fmaf(s3f, fmaxf(w4b.w, 0.f), f7)), 0.f);
  uint4 o;
  o.x = (uint_t)f2b(o0) | ((uint_t)f2b(o1) << 16);
  o.y = (uint_t)f2b(o2) | ((uint_t)f2b(o3) << 16);
  o.z = (uint_t)f2b(o4) | ((uint_t)f2b(o5) << 16);
  o.w = (uint_t)f2b(o6) | ((uint_t)f2b(o7) << 16);
  if (w2tn) {
    if (grp == 0)
      *reinterpret_cast<uint4*>(&sx[nloc * LROW + sub * 8]) = o;
    __syncthreads();
    if (wv < 4) {
      int row = lane & 15;
      int ks = (lane >> 4) * 8;
      bf16x8 a0 = *(const bf16x8*)&sx[row * LROW + ks];
      bf16x8 a1 = *(const bf16x8*)&sx[row * LROW + 32 + ks];
      int ct = wv;
      bf16x8 b0 = *(const bf16x8*)&w2tn[(ct * 16 + row) * HID + ks];
      bf16x8 b1 = *(const bf16x8*)&w2tn[(ct * 16 + row) * HID + 32 + ks];
      f32x4 acc = {0.f, 0.f, 0.f, 0.f};
      acc = __builtin_amdgcn_mfma_f32_16x16x32_bf16(a0, b0, acc, 0, 0, 0);
      acc = __builtin_amdgcn_mfma_f32_16x16x32_bf16(a1, b1, acc, 0, 0, 0);
      int rr = (lane >> 4) * 4;
      #pragma unroll
      for (int r = 0; r < 4; ++r)
        out[(size_t)(n0b + rr + r) * HID + ct * 16 + row] = f2b(acc[r]);
    }
  } else {
    if (grp == 0)
      *reinterpret_cast<uint4*>(&out[(size_t)n * HID + sub * 8]) = o;
  }
}

// Last-layer head: t = x4@W7 (MFMA), Qr[n] = sum_h relu(t)*W5hi[h] via
// shfl reduce; block-reduced column sums flushed with one atomicAdd/feature.
__global__ __launch_bounds__(256) void qdense_kernel(
    const ushort_t* __restrict__ xin, const ushort_t* __restrict__ w7t,
    const float* __restrict__ w5hi, float* __restrict__ Qr,
    float* __restrict__ sumx) {
  __shared__ float ssum[4][HID];
  int tid = threadIdx.x;
  int lane = tid & 63;
  int wloc = tid >> 6;
  int wv = (blockIdx.x * blockDim.x + tid) >> 6;
  int n0 = wv * 16;
  bool valid = n0 < NN;
  int n0c = valid ? n0 : 0;
  int row = lane & 15;
  int g = lane >> 4;
  int ks = g * 8;
  bf16x8 a0 = *(const bf16x8*)&xin[(size_t)(n0c + row) * HID + ks];
  bf16x8 a1 = *(const bf16x8*)&xin[(size_t)(n0c + row) * HID + 32 + ks];
  float r0 = 0.f, r1 = 0.f, r2 = 0.f, r3 = 0.f;
  #pragma unroll
  for (int ct = 0; ct < 4; ++ct) {
    bf16x8 b0 = *(const bf16x8*)&w7t[(ct * 16 + row) * HID + ks];
    bf16x8 b1 = *(const bf16x8*)&w7t[(ct * 16 + row) * HID + 32 + ks];
    f32x4 acc = {0.f, 0.f, 0.f, 0.f};
    acc = __builtin_amdgcn_mfma_f32_16x16x32_bf16(a0, b0, acc, 0, 0, 0);
    acc = __builtin_amdgcn_mfma_f32_16x16x32_bf16(a1, b1, acc, 0, 0, 0);
    float w5 = w5hi[ct * 16 + row];
    r0 += fmaxf(acc[0], 0.f) * w5;
    r1 += fmaxf(acc[1], 0.f) * w5;
    r2 += fmaxf(acc[2], 0.f) * w5;
    r3 += fmaxf(acc[3], 0.f) * w5;
  }
  #pragma unroll
  for (int m = 1; m <= 8; m <<= 1) {
    r0 += __shfl_xor(r0, m); r1 += __shfl_xor(r1, m);
    r2 += __shfl_xor(r2, m); r3 += __shfl_xor(r3, m);
  }
  if (valid && row == 0) {
    int rb = n0 + g * 4;
    Qr[rb + 0] = r0; Qr[rb + 1] = r1; Qr[rb + 2] = r2; Qr[rb + 3] = r3;
  }
  float c[16];
  #pragma unroll
  for (int e = 0; e < 8; ++e) {
    c[e]     = valid ? b2f((ushort_t)a0[e]) : 0.f;
    c[8 + e] = valid ? b2f((ushort_t)a1[e]) : 0.f;
  }
  #pragma unroll
  for (int m = 1; m <= 8; m <<= 1) {
    #pragma unroll
    for (int e = 0; e < 16; ++e) c[e] += __shfl_xor(c[e], m);
  }
  if (row == 0) {
    #pragma unroll
    for (int e = 0; e < 8; ++e) {
      ssum[wloc][ks + e] = c[e];
      ssum[wloc][32 + ks + e] = c[8 + e];
    }
  }
  __syncthreads();
  if (tid < HID) {
    float s = ssum[0][tid] + ssum[1][tid] + ssum[2][tid] + ssum[3][tid];
    atomicAdd(&sumx[tid], s);
  }
}

// c0 = sum_h relu(sumx @ W6)[h] * W5[h]  — single wave.
__global__ void pool_kernel(const float* __restrict__ sumx, const float* __restrict__ W6,
                            const float* __restrict__ W5, float* __restrict__ c0) {
  int lane = threadIdx.x & 63;
  float sv = sumx[lane];
  float gp = 0.f;
  #pragma unroll
  for (int k = 0; k < HID; ++k) {
    float a = __int_as_float(__builtin_amdgcn_readlane(__float_as_int(sv), k));
    gp = fmaf(a, W6[k * HID + lane], gp);
  }
  float r = fmaxf(gp, 0.f) * W5[lane];
  #pragma unroll
  for (int m = 32; m >= 1; m >>= 1) r += __shfl_xor(r, m);
  if (lane == 0) *c0 = r;
}

// Q[n] += c0 (graph-pool constant).
__global__ void qfix_kernel(float* __restrict__ Q, const float* __restrict__ c0) {
  int i = blockIdx.x * blockDim.x + threadIdx.x;
  if (i < NN) Q[i] += *c0;
}

extern "C" void kernel_launch(void* const* d_in, const int* in_sizes, int n_in,
                              void* d_out, int out_size, void* d_ws, size_t ws_size,
                              hipStream_t stream) {
  const float* x         = (const float*)d_in[0];
  const float* x_tag     = (const float*)d_in[1];
  const float* edge_attr = (const float*)d_in[2];
  const int*   edge_index= (const int*)d_in[3];
  const float* W1        = (const float*)d_in[4];
  const float* W2        = (const float*)d_in[5];
  const float* W4        = (const float*)d_in[6];
  const float* W5        = (const float*)d_in[7];
  const float* W6        = (const float*)d_in[8];
  const float* W7        = (const float*)d_in[9];
  float* Q = (float*)d_out;

  const int QBLOCKS = ((NN / 16) * 64 + 255) / 256;   // 1563
  const int NTILES  = (NE + TILE_E - 1) / TILE_E;     // 782

  char* ws = (char*)d_ws;
  size_t off = 0;
  auto alloc = [&](size_t bytes) -> void* {
    void* p = ws + off;
    off = (off + bytes + 255) & ~(size_t)255;
    return p;
  };
  // --- zeroed prefix ---
  int*      bincursor  = (int*)alloc(NBINS * 4);
  int*      bincursor2 = (int*)alloc(NBINS * 4);
  float*    sumx       = (float*)alloc(HID * 4);
  size_t zero_bytes = off;
  // --- no-zero region ---
  int*      s3i    = (int*)alloc(NN * 4);
  int*      cnt    = (int*)alloc(NN * 4);
  float*    c0     = (float*)alloc(4);
  ushort_t* xf     = (ushort_t*)alloc((size_t)NN * HID * 2);      // last-layer x
  ushort_t* yb0    = (ushort_t*)alloc((size_t)(NN + 1) * HID * 2); // +zero row
  ushort_t* yb1    = (ushort_t*)alloc((size_t)(NN + 1) * HID * 2); // +zero row
  ushort_t* w2t    = (ushort_t*)alloc((size_t)TL * HID * HID * 2);
  ushort_t* w7t    = (ushort_t*)alloc((size_t)HID * HID * 2);
  uint_t*   gbin   = (uint_t*)alloc((size_t)NBINS * BINCAP * 4);
  uint_t*   gbin2  = (uint_t*)alloc((size_t)NBINS * BINCAP * 4);

  size_t rem = (ws_size > off) ? (ws_size - off) : 0;
  int cap = (int)(rem / ((size_t)NN * 4));
  if (cap > 96) cap = 96;
  if (cap < 64) cap = 64;
  int* colidx = (int*)alloc((size_t)NN * cap * 4);

  hipMemsetAsync(d_ws, 0, zero_bytes, stream);
  hipMemsetAsync(yb0 + (size_t)NN * HID, 0, HID * 2, stream);  // sentinel rows
  hipMemsetAsync(yb1 + (size_t)NN * HID, 0, HID * 2, stream);

  escatter_kernel<<<NTILES, 256, 0, stream>>>(edge_index, edge_attr,
                                              bincursor, gbin, bincursor2, gbin2);
  bucket_kernel<<<NBINS, 256, 0, stream>>>(gbin, bincursor, colidx, cnt, cap);
  s3bucket_kernel<<<NBINS, 256, 0, stream>>>(gbin2, bincursor2, s3i);
  wconv_kernel<<<((TL + 1) * HID * HID + 255) / 256, 256, 0, stream>>>(W2, W7, w2t, w7t);

  int dblocks = ((NN / 32) * 64 + 255) / 256;
  dense_kernel<<<dblocks, 256, 0, stream>>>(x, w2t, yb0);   // y for layer 0

  int fblocks = NN / 16;                                     // 6250
  ushort_t* ycur = yb0;
  ushort_t* ynext = yb1;
  for (int l = 0; l < TL; ++l) {
    bool last = (l == TL - 1);
    aggrf_kernel<<<fblocks, 512, 0, stream>>>(
        ycur, last ? xf : ynext,
        last ? nullptr : (w2t + (size_t)(l + 1) * HID * HID),
        cnt, colidx, cap, x_tag, s3i, W1 + l * HID, W4 + l * HID);
    ushort_t* t = ycur; ycur = ynext; ynext = t;
  }

  qdense_kernel<<<QBLOCKS, 256, 0, stream>>>(xf, w7t, W5 + HID, Q, sumx);
  pool_kernel<<<1, 64, 0, stream>>>(sumx, W6, W5, c0);
  qfix_kernel<<<(NN + 255) / 256, 256, 0, stream>>>(Q, c0);
}

// Round 18
// 357.292 us; speedup vs baseline: 1.2142x; 1.1055x over previous
//
#include <hip/hip_runtime.h>

constexpr int NN  = 100000;    // nodes
constexpr int NE  = 3200000;   // edges
constexpr int HID = 64;
constexpr int TL  = 4;

constexpr int BIN_SHIFT = 9;                              // 512 nodes / bin
constexpr int BIN_NODES = 1 << BIN_SHIFT;
constexpr int NBINS     = (NN + BIN_NODES - 1) / BIN_NODES;  // 196
constexpr int BINCAP    = 18944;   // mean 16327 edges/bin, ~+20 sigma
constexpr int TILE_E    = 4096;    // edges per scatter tile (16/thread)
constexpr int PAD       = 48;      // padded neighbor-list length
constexpr int LROW      = 72;      // LDS row stride in ushorts (144 B)

typedef unsigned short ushort_t;
typedef unsigned int uint_t;
typedef unsigned char uchar_t;
typedef __attribute__((ext_vector_type(8))) short bf16x8;   // MFMA A/B frag
typedef __attribute__((ext_vector_type(4))) float f32x4;    // MFMA C/D frag

__device__ __forceinline__ ushort_t f2b(float f) {       // fp32 -> bf16 RNE
  uint_t u = __float_as_uint(f);
  u += 0x7fff + ((u >> 16) & 1);
  return (ushort_t)(u >> 16);
}
__device__ __forceinline__ float b2f(ushort_t h) {
  return __uint_as_float(((uint_t)h) << 16);
}

// Edge scatter, tile-sorted write-out. ONE (tile, stream) pair per block:
// grid = 2*NTILES, stream = blockIdx&1. ~22.6 KB LDS -> 7 blocks/CU, and
// 1564 independent blocks fill the CU slots (round-17 had 3 blocks/CU).
__global__ __launch_bounds__(256) void escatter_kernel(
    const int* __restrict__ ei, const float* __restrict__ ea,
    int* __restrict__ bincursor, uint_t* __restrict__ gbin,
    int* __restrict__ bincursor2, uint_t* __restrict__ gbin2) {
  __shared__ int hist[256];
  __shared__ int base[NBINS], offs[NBINS];
  __shared__ int wt[4];
  __shared__ uint_t  srec[TILE_E];
  __shared__ uchar_t sbin[TILE_E];
  int tid = threadIdx.x;
  int stream = blockIdx.x & 1;
  int tb = (blockIdx.x >> 1) * TILE_E;
  int lane = tid & 63;
  int wvx = tid >> 6;

  hist[tid] = 0;
  __syncthreads();
  uint_t rec[16]; int meta[16];          // meta = (bn<<12)|rk, -1 if dead
  #pragma unroll
  for (int j = 0; j < 16; ++j) {
    int e = tb + tid + j * 256;
    meta[j] = -1; rec[j] = 0;
    if (e < NE) {
      int s = ei[e];
      int bn, lo; uint_t hi;
      if (stream == 0) {
        int d = ei[NE + e];
        bn = d >> BIN_SHIFT; lo = d & (BIN_NODES - 1);
        hi = (uint_t)s;
      } else {
        bn = s >> BIN_SHIFT; lo = s & (BIN_NODES - 1);
        hi = (uint_t)(int)(ea[e] * 8388608.0f);   // ea in [0,1): 23 bits
      }
      rec[j] = (hi << BIN_SHIFT) | (uint_t)lo;
      int rk = atomicAdd(&hist[bn], 1);
      meta[j] = (bn << 12) | rk;
    }
  }
  __syncthreads();
  int c = hist[tid];
  // inclusive scan: per-wave shfl + cross-wave combine
  int v = c;
  #pragma unroll
  for (int o = 1; o < 64; o <<= 1) {
    int t = __shfl_up(v, o);
    if (lane >= o) v += t;
  }
  if (lane == 63) wt[wvx] = v;
  __syncthreads();
  for (int k = 0; k < wvx; ++k) v += wt[k];
  hist[tid] = v;                          // inclusive totals
  if (tid < NBINS) {
    offs[tid] = v - c;
    int* cur = stream ? bincursor2 : bincursor;
    base[tid] = c ? atomicAdd(&cur[tid], c) : 0;
  }
  __syncthreads();
  int total = hist[NBINS - 1];
  #pragma unroll
  for (int j = 0; j < 16; ++j) {
    if (meta[j] >= 0) {
      int bn = meta[j] >> 12, rk = meta[j] & 4095;
      int p = offs[bn] + rk;
      srec[p] = rec[j];
      sbin[p] = (uchar_t)bn;
    }
  }
  __syncthreads();
  uint_t* g = stream ? gbin2 : gbin;
  for (int t = tid; t < total; t += 256) {
    int b = sbin[t];
    int gp = base[b] + (t - offs[b]);
    if (gp < BINCAP) g[(size_t)b * BINCAP + gp] = srec[t];
  }
}

// Merged bucket + s3 kernel: 392 blocks x 512 threads.
// Blocks [0,196): colidx bucket fill (+ sentinel pad to PAD slots).
// Blocks [196,392): s3 fixed-point accumulate + coalesced store.
__global__ __launch_bounds__(512) void bucketall_kernel(
    const uint_t* __restrict__ gbin, const int* __restrict__ bincursor,
    int* __restrict__ colidx, int* __restrict__ cnt, int cap,
    const uint_t* __restrict__ gbin2, const int* __restrict__ bincursor2,
    int* __restrict__ s3i) {
  __shared__ int cur[BIN_NODES];
  int tid = threadIdx.x;
  if (blockIdx.x < NBINS) {
    int b = blockIdx.x;
    for (int i = tid; i < BIN_NODES; i += 512) cur[i] = 0;
    __syncthreads();
    int cb = min(bincursor[b], BINCAP);
    const uint_t* g = gbin + (size_t)b * BINCAP;
    for (int i = tid; i < cb; i += 512) {
      uint_t r = g[i];
      int dl = (int)(r & (BIN_NODES - 1));
      int src = (int)(r >> BIN_SHIFT);
      int pos = atomicAdd(&cur[dl], 1);
      int n = (b << BIN_SHIFT) + dl;
      if (pos < cap) colidx[(size_t)n * cap + pos] = src;
    }
    __syncthreads();
    for (int i = tid; i < BIN_NODES; i += 512) {
      int n = (b << BIN_SHIFT) + i;
      if (n < NN) cnt[n] = min(cur[i], cap);
    }
    for (int gsl = tid; gsl < BIN_NODES * 64; gsl += 512) {
      int i = gsl >> 6;
      int s = gsl & 63;
      int n = (b << BIN_SHIFT) + i;
      if (n < NN && s < PAD && s >= cur[i]) colidx[(size_t)n * cap + s] = NN;
    }
  } else {
    int b = blockIdx.x - NBINS;
    for (int i = tid; i < BIN_NODES; i += 512) cur[i] = 0;
    __syncthreads();
    int cb = min(bincursor2[b], BINCAP);
    const uint_t* g = gbin2 + (size_t)b * BINCAP;
    for (int i = tid; i < cb; i += 512) {
      uint_t r = g[i];
      atomicAdd(&cur[r & (BIN_NODES - 1)], (int)(r >> BIN_SHIFT));
    }
    __syncthreads();
    for (int i = tid; i < BIN_NODES; i += 512) {
      int n = (b << BIN_SHIFT) + i;
      if (n < NN) s3i[n] = cur[i];
    }
  }
}

// W2 [l][k][h] fp32 -> W2T [l][h][k] bf16; W7 [k][h] -> W7T [h][k] bf16.
__global__ void wconv_kernel(const float* __restrict__ W2,
                             const float* __restrict__ W7,
                             ushort_t* __restrict__ w2t,
                             ushort_t* __restrict__ w7t) {
  int i = blockIdx.x * blockDim.x + threadIdx.x;
  int tot2 = TL * HID * HID;
  if (i < tot2) {
    int l = i >> 12, r = i & 4095, h = r >> 6, k = r & 63;
    w2t[i] = f2b(W2[(size_t)l * 4096 + k * 64 + h]);
  } else if (i < tot2 + HID * HID) {
    int j = i - tot2, h = j >> 6, k = j & 63;
    w7t[j] = f2b(W7[k * 64 + h]);
  }
}

__device__ __forceinline__ bf16x8 ld8f(const float* p) {  // 8 fp32 -> bf16x8
  float4 u = *reinterpret_cast<const float4*>(p);
  float4 v = *reinterpret_cast<const float4*>(p + 4);
  bf16x8 r;
  r[0] = (short)f2b(u.x); r[1] = (short)f2b(u.y);
  r[2] = (short)f2b(u.z); r[3] = (short)f2b(u.w);
  r[4] = (short)f2b(v.x); r[5] = (short)f2b(v.y);
  r[6] = (short)f2b(v.z); r[7] = (short)f2b(v.w);
  return r;
}

// y0 = x @ W2[0] via MFMA, reading fp32 x with inline bf16 conversion.
__global__ __launch_bounds__(256) void dense_kernel(
    const float* __restrict__ xin, const ushort_t* __restrict__ wt,
    ushort_t* __restrict__ yout) {
  int lane = threadIdx.x & 63;
  int wv = (blockIdx.x * blockDim.x + threadIdx.x) >> 6;
  int n0 = wv * 32;
  if (n0 >= NN) return;
  int row = lane & 15;
  int ks = (lane >> 4) * 8;
  bf16x8 a0 = ld8f(&xin[(size_t)(n0 + row) * HID + ks]);
  bf16x8 a1 = ld8f(&xin[(size_t)(n0 + row) * HID + 32 + ks]);
  bf16x8 a2 = ld8f(&xin[(size_t)(n0 + 16 + row) * HID + ks]);
  bf16x8 a3 = ld8f(&xin[(size_t)(n0 + 16 + row) * HID + 32 + ks]);
  #pragma unroll
  for (int ct = 0; ct < 4; ++ct) {
    bf16x8 b0 = *(const bf16x8*)&wt[(ct * 16 + row) * HID + ks];
    bf16x8 b1 = *(const bf16x8*)&wt[(ct * 16 + row) * HID + 32 + ks];
    f32x4 acc0 = {0.f, 0.f, 0.f, 0.f};
    f32x4 acc1 = {0.f, 0.f, 0.f, 0.f};
    acc0 = __builtin_amdgcn_mfma_f32_16x16x32_bf16(a0, b0, acc0, 0, 0, 0);
    acc0 = __builtin_amdgcn_mfma_f32_16x16x32_bf16(a1, b1, acc0, 0, 0, 0);
    acc1 = __builtin_amdgcn_mfma_f32_16x16x32_bf16(a2, b0, acc1, 0, 0, 0);
    acc1 = __builtin_amdgcn_mfma_f32_16x16x32_bf16(a3, b1, acc1, 0, 0, 0);
    int rr = (lane >> 4) * 4;
    #pragma unroll
    for (int r = 0; r < 4; ++r) {
      yout[(size_t)(n0 + rr + r) * HID + ct * 16 + row] = f2b(acc0[r]);
      yout[(size_t)(n0 + 16 + rr + r) * HID + ct * 16 + row] = f2b(acc1[r]);
    }
  }
}

// FUSED layer kernel: gather-sum + epilogue + next-layer dense via block
// MFMA. 512 threads = 16 nodes/block.
__global__ __launch_bounds__(512) void aggrf_kernel(
    const ushort_t* __restrict__ yin, ushort_t* __restrict__ out,
    const ushort_t* __restrict__ w2tn,
    const int* __restrict__ cnt, const int* __restrict__ colidx, int cap,
    const float* __restrict__ x_tag, const int* __restrict__ s3i,
    const float* __restrict__ W1l, const float* __restrict__ W4l) {
  __shared__ ushort_t sx[16 * LROW];
  int tid = threadIdx.x;
  int lane = tid & 63;
  int wv = tid >> 6;                     // 0..7
  int n0b = blockIdx.x * 16;
  int half = lane >> 5;
  int nloc = wv * 2 + half;              // 0..15
  int n = n0b + nloc;                    // NN = 6250*16 exactly
  int grp = (lane >> 3) & 3;
  int sub = lane & 7;
  const int* cl = colidx + (size_t)n * cap + grp;
  float f0 = 0.f, f1 = 0.f, f2 = 0.f, f3 = 0.f;
  float f4 = 0.f, f5 = 0.f, f6 = 0.f, f7 = 0.f;
  uint4 w[12];
  #pragma unroll
  for (int j = 0; j < 12; ++j) {
    int c = cl[j * 4];
    w[j] = *reinterpret_cast<const uint4*>(&yin[(size_t)c * HID + sub * 8]);
  }
  #pragma unroll
  for (int j = 0; j < 12; ++j) {
    f0 += __uint_as_float(w[j].x << 16);
    f1 += __uint_as_float(w[j].x & 0xffff0000u);
    f2 += __uint_as_float(w[j].y << 16);
    f3 += __uint_as_float(w[j].y & 0xffff0000u);
    f4 += __uint_as_float(w[j].z << 16);
    f5 += __uint_as_float(w[j].z & 0xffff0000u);
    f6 += __uint_as_float(w[j].w << 16);
    f7 += __uint_as_float(w[j].w & 0xffff0000u);
  }
  int deg = cnt[n];
  if (__any(deg > PAD)) {                // rare tail (cap<=96)
    int t2 = deg - PAD;
    const int* ct2 = colidx + (size_t)n * cap + PAD;
    for (int jt = 0; jt < 12; ++jt) {
      int idx = jt * 4 + grp;
      if (idx < t2) {
        int c = ct2[idx];
        uint4 ww = *reinterpret_cast<const uint4*>(&yin[(size_t)c * HID + sub * 8]);
        f0 += __uint_as_float(ww.x << 16);
        f1 += __uint_as_float(ww.x & 0xffff0000u);
        f2 += __uint_as_float(ww.y << 16);
        f3 += __uint_as_float(ww.y & 0xffff0000u);
        f4 += __uint_as_float(ww.z << 16);
        f5 += __uint_as_float(ww.z & 0xffff0000u);
        f6 += __uint_as_float(ww.w << 16);
        f7 += __uint_as_float(ww.w & 0xffff0000u);
      }
    }
  }
  #pragma unroll
  for (int m = 8; m <= 16; m <<= 1) {
    f0 += __shfl_xor(f0, m); f1 += __shfl_xor(f1, m);
    f2 += __shfl_xor(f2, m); f3 += __shfl_xor(f3, m);
    f4 += __shfl_xor(f4, m); f5 += __shfl_xor(f5, m);
    f6 += __shfl_xor(f6, m); f7 += __shfl_xor(f7, m);
  }
  float xt = x_tag[n];
  float s3f = (float)s3i[n] * 0x1p-23f;
  float4 w1a = *reinterpret_cast<const float4*>(&W1l[sub * 8]);
  float4 w1b = *reinterpret_cast<const float4*>(&W1l[sub * 8 + 4]);
  float4 w4a = *reinterpret_cast<const float4*>(&W4l[sub * 8]);
  float4 w4b = *reinterpret_cast<const float4*>(&W4l[sub * 8 + 4]);
  float o0 = fmaxf(fmaf(xt, w1a.x, fmaf(s3f, fmaxf(w4a.x, 0.f), f0)), 0.f);
  float o1 = fmaxf(fmaf(xt, w1a.y, fmaf(s3f, fmaxf(w4a.y, 0.f), f1)), 0.f);
  float o2 = fmaxf(fmaf(xt, w1a.z, fmaf(s3f, fmaxf(w4a.z, 0.f), f2)), 0.f);
  float o3 = fmaxf(fmaf(xt, w1a.w, fmaf(s3f, fmaxf(w4a.w, 0.f), f3)), 0.f);
  float o4 = fmaxf(fmaf(xt, w1b.x, fmaf(s3f, fmaxf(w4b.x, 0.f), f4)), 0.f);
  float o5 = fmaxf(fmaf(xt, w1b.y, fmaf(s3f, fmaxf(w4b.y, 0.f), f5)), 0.f);
  float o6 = fmaxf(fmaf(xt, w1b.z, fmaf(s3f, fmaxf(w4b.z, 0.f), f6)), 0.f);
  float o7 = fmaxf(fmaf(xt, w1b.w, fmaf(s3f, fmaxf(w4b.w, 0.f), f7)), 0.f);
  uint4 o;
  o.x = (uint_t)f2b(o0) | ((uint_t)f2b(o1) << 16);
  o.y = (uint_t)f2b(o2) | ((uint_t)f2b(o3) << 16);
  o.z = (uint_t)f2b(o4) | ((uint_t)f2b(o5) << 16);
  o.w = (uint_t)f2b(o6) | ((uint_t)f2b(o7) << 16);
  if (w2tn) {
    if (grp == 0)
      *reinterpret_cast<uint4*>(&sx[nloc * LROW + sub * 8]) = o;
    __syncthreads();
    if (wv < 4) {
      int row = lane & 15;
      int ks = (lane >> 4) * 8;
      bf16x8 a0 = *(const bf16x8*)&sx[row * LROW + ks];
      bf16x8 a1 = *(const bf16x8*)&sx[row * LROW + 32 + ks];
      int ct = wv;
      bf16x8 b0 = *(const bf16x8*)&w2tn[(ct * 16 + row) * HID + ks];
      bf16x8 b1 = *(const bf16x8*)&w2tn[(ct * 16 + row) * HID + 32 + ks];
      f32x4 acc = {0.f, 0.f, 0.f, 0.f};
      acc = __builtin_amdgcn_mfma_f32_16x16x32_bf16(a0, b0, acc, 0, 0, 0);
      acc = __builtin_amdgcn_mfma_f32_16x16x32_bf16(a1, b1, acc, 0, 0, 0);
      int rr = (lane >> 4) * 4;
      #pragma unroll
      for (int r = 0; r < 4; ++r)
        out[(size_t)(n0b + rr + r) * HID + ct * 16 + row] = f2b(acc[r]);
    }
  } else {
    if (grp == 0)
      *reinterpret_cast<uint4*>(&out[(size_t)n * HID + sub * 8]) = o;
  }
}

// Last-layer head: t = x4@W7 (MFMA), Qr[n] = sum_h relu(t)*W5hi[h] via
// shfl reduce; block-reduced column sums flushed with one atomicAdd/feature.
__global__ __launch_bounds__(256) void qdense_kernel(
    const ushort_t* __restrict__ xin, const ushort_t* __restrict__ w7t,
    const float* __restrict__ w5hi, float* __restrict__ Qr,
    float* __restrict__ sumx) {
  __shared__ float ssum[4][HID];
  int tid = threadIdx.x;
  int lane = tid & 63;
  int wloc = tid >> 6;
  int wv = (blockIdx.x * blockDim.x + tid) >> 6;
  int n0 = wv * 16;
  bool valid = n0 < NN;
  int n0c = valid ? n0 : 0;
  int row = lane & 15;
  int g = lane >> 4;
  int ks = g * 8;
  bf16x8 a0 = *(const bf16x8*)&xin[(size_t)(n0c + row) * HID + ks];
  bf16x8 a1 = *(const bf16x8*)&xin[(size_t)(n0c + row) * HID + 32 + ks];
  float r0 = 0.f, r1 = 0.f, r2 = 0.f, r3 = 0.f;
  #pragma unroll
  for (int ct = 0; ct < 4; ++ct) {
    bf16x8 b0 = *(const bf16x8*)&w7t[(ct * 16 + row) * HID + ks];
    bf16x8 b1 = *(const bf16x8*)&w7t[(ct * 16 + row) * HID + 32 + ks];
    f32x4 acc = {0.f, 0.f, 0.f, 0.f};
    acc = __builtin_amdgcn_mfma_f32_16x16x32_bf16(a0, b0, acc, 0, 0, 0);
    acc = __builtin_amdgcn_mfma_f32_16x16x32_bf16(a1, b1, acc, 0, 0, 0);
    float w5 = w5hi[ct * 16 + row];
    r0 += fmaxf(acc[0], 0.f) * w5;
    r1 += fmaxf(acc[1], 0.f) * w5;
    r2 += fmaxf(acc[2], 0.f) * w5;
    r3 += fmaxf(acc[3], 0.f) * w5;
  }
  #pragma unroll
  for (int m = 1; m <= 8; m <<= 1) {
    r0 += __shfl_xor(r0, m); r1 += __shfl_xor(r1, m);
    r2 += __shfl_xor(r2, m); r3 += __shfl_xor(r3, m);
  }
  if (valid && row == 0) {
    int rb = n0 + g * 4;
    Qr[rb + 0] = r0; Qr[rb + 1] = r1; Qr[rb + 2] = r2; Qr[rb + 3] = r3;
  }
  float c[16];
  #pragma unroll
  for (int e = 0; e < 8; ++e) {
    c[e]     = valid ? b2f((ushort_t)a0[e]) : 0.f;
    c[8 + e] = valid ? b2f((ushort_t)a1[e]) : 0.f;
  }
  #pragma unroll
  for (int m = 1; m <= 8; m <<= 1) {
    #pragma unroll
    for (int e = 0; e < 16; ++e) c[e] += __shfl_xor(c[e], m);
  }
  if (row == 0) {
    #pragma unroll
    for (int e = 0; e < 8; ++e) {
      ssum[wloc][ks + e] = c[e];
      ssum[wloc][32 + ks + e] = c[8 + e];
    }
  }
  __syncthreads();
  if (tid < HID) {
    float s = ssum[0][tid] + ssum[1][tid] + ssum[2][tid] + ssum[3][tid];
    atomicAdd(&sumx[tid], s);
  }
}

// c0 = sum_h relu(sumx @ W6)[h] * W5[h]  — single wave.
__global__ void pool_kernel(const float* __restrict__ sumx, const float* __restrict__ W6,
                            const float* __restrict__ W5, float* __restrict__ c0) {
  int lane = threadIdx.x & 63;
  float sv = sumx[lane];
  float gp = 0.f;
  #pragma unroll
  for (int k = 0; k < HID; ++k) {
    float a = __int_as_float(__builtin_amdgcn_readlane(__float_as_int(sv), k));
    gp = fmaf(a, W6[k * HID + lane], gp);
  }
  float r = fmaxf(gp, 0.f) * W5[lane];
  #pragma unroll
  for (int m = 32; m >= 1; m >>= 1) r += __shfl_xor(r, m);
  if (lane == 0) *c0 = r;
}

// Q[n] += c0 (graph-pool constant).
__global__ void qfix_kernel(float* __restrict__ Q, const float* __restrict__ c0) {
  int i = blockIdx.x * blockDim.x + threadIdx.x;
  if (i < NN) Q[i] += *c0;
}

extern "C" void kernel_launch(void* const* d_in, const int* in_sizes, int n_in,
                              void* d_out, int out_size, void* d_ws, size_t ws_size,
                              hipStream_t stream) {
  const float* x         = (const float*)d_in[0];
  const float* x_tag     = (const float*)d_in[1];
  const float* edge_attr = (const float*)d_in[2];
  const int*   edge_index= (const int*)d_in[3];
  const float* W1        = (const float*)d_in[4];
  const float* W2        = (const float*)d_in[5];
  const float* W4        = (const float*)d_in[6];
  const float* W5        = (const float*)d_in[7];
  const float* W6        = (const float*)d_in[8];
  const float* W7        = (const float*)d_in[9];
  float* Q = (float*)d_out;

  const int QBLOCKS = ((NN / 16) * 64 + 255) / 256;   // 1563
  const int NTILES  = (NE + TILE_E - 1) / TILE_E;     // 782

  char* ws = (char*)d_ws;
  size_t off = 0;
  auto alloc = [&](size_t bytes) -> void* {
    void* p = ws + off;
    off = (off + bytes + 255) & ~(size_t)255;
    return p;
  };
  // --- zeroed prefix ---
  int*      bincursor  = (int*)alloc(NBINS * 4);
  int*      bincursor2 = (int*)alloc(NBINS * 4);
  float*    sumx       = (float*)alloc(HID * 4);
  size_t zero_bytes = off;
  // --- no-zero region ---
  int*      s3i    = (int*)alloc(NN * 4);
  int*      cnt    = (int*)alloc(NN * 4);
  float*    c0     = (float*)alloc(4);
  ushort_t* xf     = (ushort_t*)alloc((size_t)NN * HID * 2);      // last-layer x
  ushort_t* yb0    = (ushort_t*)alloc((size_t)(NN + 1) * HID * 2); // +zero row
  ushort_t* yb1    = (ushort_t*)alloc((size_t)(NN + 1) * HID * 2); // +zero row
  ushort_t* w2t    = (ushort_t*)alloc((size_t)TL * HID * HID * 2);
  ushort_t* w7t    = (ushort_t*)alloc((size_t)HID * HID * 2);
  uint_t*   gbin   = (uint_t*)alloc((size_t)NBINS * BINCAP * 4);
  uint_t*   gbin2  = (uint_t*)alloc((size_t)NBINS * BINCAP * 4);

  size_t rem = (ws_size > off) ? (ws_size - off) : 0;
  int cap = (int)(rem / ((size_t)NN * 4));
  if (cap > 96) cap = 96;
  if (cap < 64) cap = 64;
  int* colidx = (int*)alloc((size_t)NN * cap * 4);

  hipMemsetAsync(d_ws, 0, zero_bytes, stream);
  hipMemsetAsync(yb0 + (size_t)NN * HID, 0, HID * 2, stream);  // sentinel rows
  hipMemsetAsync(yb1 + (size_t)NN * HID, 0, HID * 2, stream);

  escatter_kernel<<<NTILES * 2, 256, 0, stream>>>(edge_index, edge_attr,
                                                  bincursor, gbin, bincursor2, gbin2);
  bucketall_kernel<<<NBINS * 2, 512, 0, stream>>>(gbin, bincursor, colidx, cnt, cap,
                                                  gbin2, bincursor2, s3i);
  wconv_kernel<<<((TL + 1) * HID * HID + 255) / 256, 256, 0, stream>>>(W2, W7, w2t, w7t);

  int dblocks = ((NN / 32) * 64 + 255) / 256;
  dense_kernel<<<dblocks, 256, 0, stream>>>(x, w2t, yb0);   // y for layer 0

  int fblocks = NN / 16;                                     // 6250
  ushort_t* ycur = yb0;
  ushort_t* ynext = yb1;
  for (int l = 0; l < TL; ++l) {
    bool last = (l == TL - 1);
    aggrf_kernel<<<fblocks, 512, 0, stream>>>(
        ycur, last ? xf : ynext,
        last ? nullptr : (w2t + (size_t)(l + 1) * HID * HID),
        cnt, colidx, cap, x_tag, s3i, W1 + l * HID, W4 + l * HID);
    ushort_t* t = ycur; ycur = ynext; ynext = t;
  }

  qdense_kernel<<<QBLOCKS, 256, 0, stream>>>(xf, w7t, W5 + HID, Q, sumx);
  pool_kernel<<<1, 64, 0, stream>>>(sumx, W6, W5, c0);
  qfix_kernel<<<(NN + 255) / 256, 256, 0, stream>>>(Q, c0);
}